// Round 1
// 1303.494 us; speedup vs baseline: 1.3240x; 1.3240x over previous
//
#include <hip/hip_runtime.h>
#include <cmath>

#define DD 64

namespace {

constexpr int U_N = 50000, B_N = 20000, I_N = 100000;
constexpr int BATCH = 2048;

// phase-1 CSR: 340000 rows, bucket = row >> 10 (1024 rows/bucket, 333 buckets)
// phase-2 CSR: 70000 rows,  bucket = row >> 8  (256 rows/bucket, 274 buckets)
constexpr int N1 = 340000, N2 = 70000;
constexpr int SHIFT1 = 10, SHIFT2 = 8;
constexpr int NB1 = (N1 + (1 << SHIFT1) - 1) >> SHIFT1;  // 333
constexpr int NB2 = (N2 + (1 << SHIFT2) - 1) >> SHIFT2;  // 274

typedef __attribute__((ext_vector_type(8))) short short8;   // 8 bf16 (4 VGPRs)
typedef __attribute__((ext_vector_type(4))) float floatx4;  // 4 fp32 acc

__device__ __forceinline__ float wave_sum(float v) {
#pragma unroll
  for (int off = 32; off > 0; off >>= 1) v += __shfl_xor(v, off);
  return v;
}

__device__ __forceinline__ unsigned short f2bf(float f) {
  unsigned u = __float_as_uint(f);
  unsigned r = (u + 0x7FFFu + ((u >> 16) & 1u)) >> 16;  // RNE
  return (unsigned short)r;
}

// out = concat(A, Bf) * (1/3)   (layer-0 term, unnormalized)
__global__ void k_init0(const float* __restrict__ A, const float* __restrict__ Bf,
                        float* __restrict__ out, int nA, int nTot) {
  int idx = blockIdx.x * 256 + threadIdx.x;
  int tot4 = nTot * (DD / 4);
  if (idx >= tot4) return;
  int nA4 = nA * (DD / 4);
  float4 v = (idx < nA4) ? ((const float4*)A)[idx] : ((const float4*)Bf)[idx - nA4];
  float4 o;
  o.x = v.x * (1.f / 3.f); o.y = v.y * (1.f / 3.f);
  o.z = v.z * (1.f / 3.f); o.w = v.w * (1.f / 3.f);
  ((float4*)out)[idx] = o;
}

// ---------------- CSR build (two-pass bucketed binning) ----------------
// Pass 0: coarse bucket histogram (LDS-staged, streaming read of rows).
__global__ __launch_bounds__(512) void k_bhist(const int* __restrict__ rows, int nnz,
                                               int row_off, int shift,
                                               int* __restrict__ bcnt) {
  __shared__ int h[512];
  int t = threadIdx.x;
  h[t] = 0;
  __syncthreads();
  int tile0 = blockIdx.x * 8192;
#pragma unroll
  for (int i = 0; i < 16; ++i) {
    int e = tile0 + i * 512 + t;
    if (e < nnz) atomicAdd(&h[(rows[e] + row_off) >> shift], 1);
  }
  __syncthreads();
  if (h[t]) atomicAdd(&bcnt[t], h[t]);
}

// single-block exclusive scan of <=512 bucket counts -> base & cursor; also rowptr[N]=total
__global__ void k_bucket_scan(const int* __restrict__ bcnt, int nb, int* __restrict__ bbase,
                              int* __restrict__ bcur, int* __restrict__ rowptr_end, int total) {
  int t = threadIdx.x;  // 512
  int lane = t & 63, w = t >> 6;
  int v = (t < nb) ? bcnt[t] : 0;
  int inc = v;
#pragma unroll
  for (int off = 1; off < 64; off <<= 1) {
    int y = __shfl_up(inc, off);
    if (lane >= off) inc += y;
  }
  __shared__ int wsum[8];
  if (lane == 63) wsum[w] = inc;
  __syncthreads();
  int wadd = 0;
  for (int i = 0; i < w; ++i) wadd += wsum[i];
  inc += wadd;
  if (t < nb) { bbase[t] = inc - v; bcur[t] = inc - v; }
  if (t == 0) { bbase[nb] = total; *rowptr_end = total; }
}

// Pass 1: bin edges into bucket-grouped staging arrays with per-tile run reservation.
// Writes are contiguous runs (~tile/NB edges) -> near-full-line HBM writes.
__global__ __launch_bounds__(512) void k_binscatter(const int* __restrict__ rows,
                                                    const int* __restrict__ cols,
                                                    const float* __restrict__ vals, int nnz,
                                                    int row_off, int shift,
                                                    int* __restrict__ bcur,
                                                    int* __restrict__ ebin_r,
                                                    int2* __restrict__ ebin_cv) {
  __shared__ int cnt[512];
  __shared__ int gbase[512];
  int t = threadIdx.x;
  int tile0 = blockIdx.x * 8192;
  cnt[t] = 0;
  __syncthreads();
  int r[16], rank[16];
#pragma unroll
  for (int i = 0; i < 16; ++i) {
    int e = tile0 + i * 512 + t;
    if (e < nnz) {
      r[i] = rows[e] + row_off;
      rank[i] = atomicAdd(&cnt[r[i] >> shift], 1);
    }
  }
  __syncthreads();
  int c = cnt[t];
  if (c > 0) gbase[t] = atomicAdd(&bcur[t], c);
  __syncthreads();
#pragma unroll
  for (int i = 0; i < 16; ++i) {
    int e = tile0 + i * 512 + t;
    if (e < nnz) {
      int pos = gbase[r[i] >> shift] + rank[i];
      ebin_r[pos] = r[i];
      ebin_cv[pos] = make_int2(cols[e], __float_as_int(vals[e]));
    }
  }
}

// Pass 2: one workgroup per bucket. LDS row-hist + in-block scan writes rowptr directly
// (no global per-row hist / global scan needed); then exact placement via LDS cursors.
// Bucket's epack region (~125 KB) is written by one block -> one XCD -> full-line evicts.
__global__ __launch_bounds__(1024) void k_place(const int* __restrict__ bbase, int shift,
                                                int nrows, const int* __restrict__ ebin_r,
                                                const int2* __restrict__ ebin_cv,
                                                int* __restrict__ rowptr,
                                                int2* __restrict__ epack) {
  int b = blockIdx.x;
  int bsize = 1 << shift;
  int row0 = b << shift;
  int t = threadIdx.x;
  __shared__ int rcnt[1024];
  __shared__ int wsum[16];
  int ebase = bbase[b], eend = bbase[b + 1];
  if (t < bsize) rcnt[t] = 0;
  __syncthreads();
  for (int e = ebase + t; e < eend; e += 1024)
    atomicAdd(&rcnt[ebin_r[e] - row0], 1);
  __syncthreads();
  int v = (t < bsize) ? rcnt[t] : 0;
  int inc = v;
  int lane = t & 63, w = t >> 6;
#pragma unroll
  for (int off = 1; off < 64; off <<= 1) {
    int y = __shfl_up(inc, off);
    if (lane >= off) inc += y;
  }
  if (lane == 63) wsum[w] = inc;
  __syncthreads();
  int wadd = 0;
  for (int i = 0; i < w; ++i) wadd += wsum[i];
  inc += wadd;
  int excl = inc - v;  // exclusive scan of per-row counts within bucket
  int nr = nrows - row0;
  if (nr > bsize) nr = bsize;
  if (t < nr) rowptr[row0 + t] = ebase + excl;
  __syncthreads();
  if (t < bsize) rcnt[t] = excl;  // reuse as cursor
  __syncthreads();
  for (int e = ebase + t; e < eend; e += 1024) {
    int r = ebin_r[e] - row0;
    int pos = ebase + atomicAdd(&rcnt[r], 1);
    epack[pos] = ebin_cv[e];
  }
}

// ---------------- fused gather SPMM (4 edges x float4 lanes per wave) ----------------

__global__ void k_spmm_prop(const int* __restrict__ rowptr, const int2* __restrict__ epack,
                            const float* __restrict__ xA, const float* __restrict__ xB,
                            int nA, const float* __restrict__ noise,
                            float* __restrict__ fout, float* __restrict__ outp,
                            int n, int write_f) {
  long long t = (long long)blockIdx.x * 256 + threadIdx.x;
  int row = (int)(t >> 6), lane = (int)(t & 63);
  if (row >= n) return;
  int q = lane >> 4, c = lane & 15;
  int s = rowptr[row], e = rowptr[row + 1];
  float4 a0 = {0.f, 0.f, 0.f, 0.f}, a1 = {0.f, 0.f, 0.f, 0.f};
  for (int kk = s; kk < e; kk += 8) {
    int i0 = kk + q, i1 = kk + 4 + q;
    int2 e0 = (i0 < e) ? epack[i0] : make_int2(0, 0);
    int2 e1 = (i1 < e) ? epack[i1] : make_int2(0, 0);
    const float* p0 = (e0.x < nA) ? (xA + (size_t)e0.x * DD)
                                  : (xB + (size_t)(e0.x - nA) * DD);
    const float* p1 = (e1.x < nA) ? (xA + (size_t)e1.x * DD)
                                  : (xB + (size_t)(e1.x - nA) * DD);
    float4 x0 = ((const float4*)p0)[c];
    float4 x1 = ((const float4*)p1)[c];
    float v0 = __int_as_float(e0.y), v1 = __int_as_float(e1.y);
    a0.x = fmaf(v0, x0.x, a0.x); a0.y = fmaf(v0, x0.y, a0.y);
    a0.z = fmaf(v0, x0.z, a0.z); a0.w = fmaf(v0, x0.w, a0.w);
    a1.x = fmaf(v1, x1.x, a1.x); a1.y = fmaf(v1, x1.y, a1.y);
    a1.z = fmaf(v1, x1.z, a1.z); a1.w = fmaf(v1, x1.w, a1.w);
  }
  float4 g;
  g.x = a0.x + a1.x; g.y = a0.y + a1.y; g.z = a0.z + a1.z; g.w = a0.w + a1.w;
  g.x += __shfl_xor(g.x, 16); g.y += __shfl_xor(g.y, 16);
  g.z += __shfl_xor(g.z, 16); g.w += __shfl_xor(g.w, 16);
  g.x += __shfl_xor(g.x, 32); g.y += __shfl_xor(g.y, 32);
  g.z += __shfl_xor(g.z, 32); g.w += __shfl_xor(g.w, 32);
  float4 nz = ((const float4*)(noise + (size_t)row * DD))[c];
  float nn = wave_sum(nz.x * nz.x + nz.y * nz.y + nz.z * nz.z + nz.w * nz.w) * 0.25f;
  float nf = 0.1f / fmaxf(sqrtf(nn), 1e-12f);
  float4 fv;
  fv.x = g.x + ((g.x > 0.f) ? 1.f : ((g.x < 0.f) ? -1.f : 0.f)) * nz.x * nf;
  fv.y = g.y + ((g.y > 0.f) ? 1.f : ((g.y < 0.f) ? -1.f : 0.f)) * nz.y * nf;
  fv.z = g.z + ((g.z > 0.f) ? 1.f : ((g.z < 0.f) ? -1.f : 0.f)) * nz.z * nf;
  fv.w = g.w + ((g.w > 0.f) ? 1.f : ((g.w < 0.f) ? -1.f : 0.f)) * nz.w * nf;
  float fn = wave_sum(fv.x * fv.x + fv.y * fv.y + fv.z * fv.z + fv.w * fv.w) * 0.25f;
  float inv = (1.f / 3.f) / fmaxf(sqrtf(fn), 1e-12f);
  if (lane < 16) {
    if (write_f) ((float4*)(fout + (size_t)row * DD))[c] = fv;
    float4 o = ((float4*)(outp + (size_t)row * DD))[c];
    o.x += fv.x * inv; o.y += fv.y * inv; o.z += fv.z * inv; o.w += fv.w * inv;
    ((float4*)(outp + (size_t)row * DD))[c] = o;
  }
}

__global__ void k_spmm_agg(const int* __restrict__ rowptr, const int2* __restrict__ epack,
                           const float* __restrict__ x, const float* __restrict__ noise,
                           float* __restrict__ out, int n) {
  long long t = (long long)blockIdx.x * 256 + threadIdx.x;
  int row = (int)(t >> 6), lane = (int)(t & 63);
  if (row >= n) return;
  int q = lane >> 4, c = lane & 15;
  int s = rowptr[row], e = rowptr[row + 1];
  float4 a0 = {0.f, 0.f, 0.f, 0.f}, a1 = {0.f, 0.f, 0.f, 0.f};
  for (int kk = s; kk < e; kk += 8) {
    int i0 = kk + q, i1 = kk + 4 + q;
    int2 e0 = (i0 < e) ? epack[i0] : make_int2(0, 0);
    int2 e1 = (i1 < e) ? epack[i1] : make_int2(0, 0);
    float4 x0 = ((const float4*)(x + (size_t)e0.x * DD))[c];
    float4 x1 = ((const float4*)(x + (size_t)e1.x * DD))[c];
    float v0 = __int_as_float(e0.y), v1 = __int_as_float(e1.y);
    a0.x = fmaf(v0, x0.x, a0.x); a0.y = fmaf(v0, x0.y, a0.y);
    a0.z = fmaf(v0, x0.z, a0.z); a0.w = fmaf(v0, x0.w, a0.w);
    a1.x = fmaf(v1, x1.x, a1.x); a1.y = fmaf(v1, x1.y, a1.y);
    a1.z = fmaf(v1, x1.z, a1.z); a1.w = fmaf(v1, x1.w, a1.w);
  }
  float4 g;
  g.x = a0.x + a1.x; g.y = a0.y + a1.y; g.z = a0.z + a1.z; g.w = a0.w + a1.w;
  g.x += __shfl_xor(g.x, 16); g.y += __shfl_xor(g.y, 16);
  g.z += __shfl_xor(g.z, 16); g.w += __shfl_xor(g.w, 16);
  g.x += __shfl_xor(g.x, 32); g.y += __shfl_xor(g.y, 32);
  g.z += __shfl_xor(g.z, 32); g.w += __shfl_xor(g.w, 32);
  float4 nz = ((const float4*)(noise + (size_t)row * DD))[c];
  float nn = wave_sum(nz.x * nz.x + nz.y * nz.y + nz.z * nz.z + nz.w * nz.w) * 0.25f;
  float nf = 0.1f / fmaxf(sqrtf(nn), 1e-12f);
  if (lane < 16) {
    float4 fv;
    fv.x = g.x + ((g.x > 0.f) ? 1.f : ((g.x < 0.f) ? -1.f : 0.f)) * nz.x * nf;
    fv.y = g.y + ((g.y > 0.f) ? 1.f : ((g.y < 0.f) ? -1.f : 0.f)) * nz.y * nf;
    fv.z = g.z + ((g.z > 0.f) ? 1.f : ((g.z < 0.f) ? -1.f : 0.f)) * nz.z * nf;
    fv.w = g.w + ((g.w > 0.f) ? 1.f : ((g.w < 0.f) ? -1.f : 0.f)) * nz.w * nf;
    ((float4*)(out + (size_t)row * DD))[c] = fv;
  }
}

// ---------------- heads ----------------

__global__ void k_bpr(const float* __restrict__ o_UI, const float* __restrict__ biu,
                      const float* __restrict__ uib, const float* __restrict__ o_BI,
                      const int* __restrict__ users, const int* __restrict__ bundles,
                      float* __restrict__ bpr_terms) {
  long long t = (long long)blockIdx.x * 256 + threadIdx.x;
  int w = (int)(t >> 6);
  int lane = (int)(t & 63);
  if (w >= BATCH) return;
  int u = users[w];
  int b0 = bundles[2 * w], b1 = bundles[2 * w + 1];
  float ur = 0.5f * (o_UI[(size_t)u * DD + lane] + biu[(size_t)u * DD + lane]);
  float br0 = 0.5f * (uib[(size_t)b0 * DD + lane] + o_BI[(size_t)b0 * DD + lane]);
  float br1 = 0.5f * (uib[(size_t)b1 * DD + lane] + o_BI[(size_t)b1 * DD + lane]);
  float pos = wave_sum(ur * br0);
  float neg = wave_sum(ur * br1);
  if (lane == 0) {
    float x = pos - neg;
    float loss = (x > 0.f) ? log1pf(expf(-x)) : (-x + log1pf(expf(x)));
    bpr_terms[w] = loss;
  }
}

__global__ void k_sumsq_p(const float* __restrict__ x, int n4, float* __restrict__ partials) {
  float s = 0.f;
  for (int i = blockIdx.x * 256 + threadIdx.x; i < n4; i += gridDim.x * 256) {
    float4 v = ((const float4*)x)[i];
    s += v.x * v.x + v.y * v.y + v.z * v.z + v.w * v.w;
  }
  s = wave_sum(s);
  __shared__ float part[4];
  if ((threadIdx.x & 63) == 0) part[threadIdx.x >> 6] = s;
  __syncthreads();
  if (threadIdx.x == 0) partials[blockIdx.x] = part[0] + part[1] + part[2] + part[3];
}

// build 6 normalized (2048 x 64) matrices, fp32 + bf16 copies
__global__ void k_gather(const float* __restrict__ o_UB, const float* __restrict__ o_UI,
                         const float* __restrict__ o_BI, const float* __restrict__ uib,
                         const float* __restrict__ biu, const int* __restrict__ users,
                         const int* __restrict__ bundles, float* __restrict__ P,
                         unsigned short* __restrict__ Pb) {
  long long t = (long long)blockIdx.x * 256 + threadIdx.x;
  int w = (int)(t >> 6);
  int lane = (int)(t & 63);
  if (w >= 6 * BATCH) return;
  int k = w / BATCH, b = w % BATCH;
  const float* src;
  if (k == 0)      src = o_UB + (size_t)users[b] * DD;
  else if (k == 1) src = o_UI + (size_t)users[b] * DD;
  else if (k == 2) src = biu + (size_t)users[b] * DD;
  else if (k == 3) src = o_UB + (size_t)(U_N + bundles[2 * b]) * DD;
  else if (k == 4) src = uib + (size_t)bundles[2 * b] * DD;
  else             src = o_BI + (size_t)bundles[2 * b] * DD;
  float v = src[lane];
  float n2 = wave_sum(v * v);
  float inv = 1.f / fmaxf(sqrtf(n2), 1e-12f);
  float pv = v * inv;
  P[(size_t)w * DD + lane] = pv;
  Pb[(size_t)w * DD + lane] = f2bf(pv);
}

// MFMA CL pair kernel: each wave computes a 64x256 S-chunk of one pair,
// ttl[p][i] += sum_j exp(4 * X_i . Y_j)   (atomic partial row-sums)
__global__ void k_clpair_mfma(const unsigned short* __restrict__ Pb,
                              float* __restrict__ ttl) {
  const int pairX[12] = {0, 0, 1, 0, 1, 2, 3, 3, 4, 3, 4, 5};
  const int pairY[12] = {1, 2, 2, 0, 1, 2, 4, 5, 5, 3, 4, 5};
  int wid = threadIdx.x >> 6;
  int lane = threadIdx.x & 63;
  int wtile = blockIdx.x * 4 + wid;     // 12 * 32 * 8 = 3072 wave-tiles
  int p = wtile >> 8;                   // / 256
  int rest = wtile & 255;
  int it = rest >> 3, jc = rest & 7;    // 64-row i-tile, 256-col j-chunk
  const unsigned short* X = Pb + (size_t)pairX[p] * BATCH * DD;
  const unsigned short* Y = Pb + (size_t)pairY[p] * BATCH * DD;
  int r = lane & 15, q = lane >> 4;
  // A-frags for the wave's 64 rows, both K-halves (A[m=lane&15][k=q*8+j])
  short8 A[2][4];
#pragma unroll
  for (int kh = 0; kh < 2; ++kh)
#pragma unroll
    for (int ii = 0; ii < 4; ++ii)
      A[kh][ii] = *(const short8*)(X + (size_t)(it * 64 + ii * 16 + r) * DD + kh * 32 + q * 8);
  float rs[4][4];  // [ii][reg] row-sums of exp
#pragma unroll
  for (int ii = 0; ii < 4; ++ii)
#pragma unroll
    for (int g = 0; g < 4; ++g) rs[ii][g] = 0.f;
  for (int jn = 0; jn < 4; ++jn) {
    int j0 = jc * 256 + jn * 64;
    floatx4 acc[4][4];
#pragma unroll
    for (int ii = 0; ii < 4; ++ii)
#pragma unroll
      for (int jj = 0; jj < 4; ++jj) acc[ii][jj] = (floatx4){0.f, 0.f, 0.f, 0.f};
#pragma unroll
    for (int kh = 0; kh < 2; ++kh) {
      short8 Bf[4];
#pragma unroll
      for (int jj = 0; jj < 4; ++jj)
        Bf[jj] = *(const short8*)(Y + (size_t)(j0 + jj * 16 + r) * DD + kh * 32 + q * 8);
#pragma unroll
      for (int ii = 0; ii < 4; ++ii)
#pragma unroll
        for (int jj = 0; jj < 4; ++jj)
          acc[ii][jj] = __builtin_amdgcn_mfma_f32_16x16x32_bf16(A[kh][ii], Bf[jj],
                                                                acc[ii][jj], 0, 0, 0);
    }
#pragma unroll
    for (int ii = 0; ii < 4; ++ii)
#pragma unroll
      for (int jj = 0; jj < 4; ++jj)
#pragma unroll
        for (int g = 0; g < 4; ++g) rs[ii][g] += __expf(4.0f * acc[ii][jj][g]);
  }
  // reduce over the 16 cols held across lanes sharing q (C/D: col=lane&15, row=q*4+reg)
#pragma unroll
  for (int off = 1; off < 16; off <<= 1)
#pragma unroll
    for (int ii = 0; ii < 4; ++ii)
#pragma unroll
      for (int g = 0; g < 4; ++g) rs[ii][g] += __shfl_xor(rs[ii][g], off);
  if (r == 0) {
#pragma unroll
    for (int ii = 0; ii < 4; ++ii)
#pragma unroll
      for (int g = 0; g < 4; ++g)
        unsafeAtomicAdd(&ttl[(size_t)p * BATCH + it * 64 + ii * 16 + q * 4 + g],
                        rs[ii][g]);
  }
}

// per (pair, i): ttl[p,i] <- log(ttl[p,i]) - diag/tau  (diag in fp32)
__global__ void k_cldiag(const float* __restrict__ P, float* __restrict__ ttl) {
  const int pairX[12] = {0, 0, 1, 0, 1, 2, 3, 3, 4, 3, 4, 5};
  const int pairY[12] = {1, 2, 2, 0, 1, 2, 4, 5, 5, 3, 4, 5};
  long long t = (long long)blockIdx.x * 256 + threadIdx.x;
  int w = (int)(t >> 6);
  int lane = (int)(t & 63);
  if (w >= 12 * BATCH) return;
  int p = w / BATCH, i = w % BATCH;
  float xv = P[((size_t)pairX[p] * BATCH + i) * DD + lane];
  float yv = P[((size_t)pairY[p] * BATCH + i) * DD + lane];
  float d = wave_sum(xv * yv);
  if (lane == 0) ttl[(size_t)p * BATCH + i] = logf(ttl[(size_t)p * BATCH + i]) - d * 4.0f;
}

__global__ void k_finalred(const float* __restrict__ bpr_terms,
                           const float* __restrict__ cl_terms,
                           const float* __restrict__ partials,
                           float* __restrict__ out) {
  int t = threadIdx.x;  // 1024
  float bpr = 0.f, reg = 0.f, inter = 0.f, intra = 0.f;
  for (int i = t; i < BATCH; i += 1024) bpr += bpr_terms[i];
  for (int i = t; i < 768; i += 1024) reg += partials[i];
  for (int i = t; i < 12 * BATCH; i += 1024) {
    int p = i >> 11;
    float v = cl_terms[i];
    if ((p % 6) < 3) inter += v; else intra += v;
  }
  bpr = wave_sum(bpr); reg = wave_sum(reg);
  inter = wave_sum(inter); intra = wave_sum(intra);
  __shared__ float sb[16], sr[16], si[16], sx[16];
  int w = t >> 6, lane = t & 63;
  if (lane == 0) { sb[w] = bpr; sr[w] = reg; si[w] = inter; sx[w] = intra; }
  __syncthreads();
  if (t == 0) {
    float Bs = 0, Rs = 0, Is = 0, Xs = 0;
    for (int i = 0; i < 16; ++i) { Bs += sb[i]; Rs += sr[i]; Is += si[i]; Xs += sx[i]; }
    out[0] = Bs / (float)BATCH + 1e-5f * Rs;
    out[1] = 0.04f * (0.5f * Is + 0.5f * Xs) / (float)BATCH;
  }
}

}  // namespace

extern "C" void kernel_launch(void* const* d_in, const int* in_sizes, int n_in,
                              void* d_out, int out_size, void* d_ws, size_t ws_size,
                              hipStream_t stream) {
  const float* usersF = (const float*)d_in[0];
  const float* bundlesF = (const float*)d_in[1];
  const float* itemsF = (const float*)d_in[2];
  const int* ub_rows = (const int*)d_in[3];
  const int* ub_cols = (const int*)d_in[4];
  const float* ub_vals = (const float*)d_in[5];
  const int* ui_rows = (const int*)d_in[6];
  const int* ui_cols = (const int*)d_in[7];
  const float* ui_vals = (const float*)d_in[8];
  const int* bi_rows = (const int*)d_in[9];
  const int* bi_cols = (const int*)d_in[10];
  const float* bi_vals = (const float*)d_in[11];
  const int* biagg_rows = (const int*)d_in[12];
  const int* biagg_cols = (const int*)d_in[13];
  const float* biagg_vals = (const float*)d_in[14];
  const int* uiagg_rows = (const int*)d_in[15];
  const int* uiagg_cols = (const int*)d_in[16];
  const float* uiagg_vals = (const float*)d_in[17];
  const float* noise_UB = (const float*)d_in[18];
  const float* noise_UI = (const float*)d_in[19];
  const float* noise_BI = (const float*)d_in[20];
  const float* noise_agg_BI = (const float*)d_in[21];
  const float* noise_agg_UI = (const float*)d_in[22];
  const int* users = (const int*)d_in[23];
  const int* bundles = (const int*)d_in[24];
  int nnz_ub = in_sizes[3], nnz_ui = in_sizes[6], nnz_bi = in_sizes[9];
  int nnz_biagg = in_sizes[12], nnz_uiagg = in_sizes[15];
  int nnzTot1 = nnz_ub + nnz_ui + nnz_bi;
  int nnzTot2 = nnz_biagg + nnz_uiagg;

  float* ws = (float*)d_ws;
  size_t off = 0;
  float* o_UB = ws + off; off += (size_t)(U_N + B_N) * DD;
  float* o_UI = ws + off; off += (size_t)(U_N + I_N) * DD;
  float* o_BI = ws + off; off += (size_t)(B_N + I_N) * DD;
  float* uib  = ws + off; off += (size_t)B_N * DD;
  float* biu  = ws + off; off += (size_t)U_N * DD;
  float* s2   = ws + off; off += (size_t)(U_N + I_N) * DD;
  float* P    = ws + off; off += (size_t)6 * BATCH * DD;
  float* ttl  = ws + off; off += (size_t)12 * BATCH;
  float* bprT = ws + off; off += BATCH;
  float* prt  = ws + off; off += 768;
  // Pb (bf16 copy of P) aliases s2: s2 is dead after the last spmm_prop
  unsigned short* Pb = (unsigned short*)s2;
  int* rptr  = (int*)(ws + off); off += N1 + 1;
  int* bcnt  = (int*)(ws + off); off += 512;
  int* bbase = (int*)(ws + off); off += 520;
  int* bcur  = (int*)(ws + off); off += 512;
  off = (off + 1) & ~(size_t)1;  // 8B align
  int2* epack = (int2*)(ws + off); off += (size_t)5200000 * 2;
  if (ws_size < off * sizeof(float)) return;  // insufficient workspace

  // binning staging buffers alias dead regions:
  // phase 1 (before any propagate): o_UB/o_UI/o_BI region (21.76M floats >= 15.6M needed)
  int2* ebin_cv1 = (int2*)ws;
  int*  ebin_r1  = (int*)ws + (size_t)2 * nnzTot1;
  // phase 2 (after propagates, s2 dead): s2 region (9.6M floats >= 5.4M needed)
  int2* ebin_cv2 = (int2*)s2;
  int*  ebin_r2  = (int*)s2 + (size_t)2 * nnzTot2;

  auto gb = [](int nnz) { return (nnz + 8191) / 8192; };

  // ---- phase-1 CSR: UB rows [0,70000), UI rows [70000,220000), BI rows [220000,340000)
  int* rp_ub = rptr, * rp_ui = rptr + 70000, * rp_bi = rptr + 220000;
  hipMemsetAsync(bcnt, 0, 512 * sizeof(int), stream);
  k_bhist<<<gb(nnz_ub), 512, 0, stream>>>(ub_rows, nnz_ub, 0, SHIFT1, bcnt);
  k_bhist<<<gb(nnz_ui), 512, 0, stream>>>(ui_rows, nnz_ui, 70000, SHIFT1, bcnt);
  k_bhist<<<gb(nnz_bi), 512, 0, stream>>>(bi_rows, nnz_bi, 220000, SHIFT1, bcnt);
  k_bucket_scan<<<1, 512, 0, stream>>>(bcnt, NB1, bbase, bcur, rptr + N1, nnzTot1);
  k_binscatter<<<gb(nnz_ub), 512, 0, stream>>>(ub_rows, ub_cols, ub_vals, nnz_ub, 0, SHIFT1,
                                               bcur, ebin_r1, ebin_cv1);
  k_binscatter<<<gb(nnz_ui), 512, 0, stream>>>(ui_rows, ui_cols, ui_vals, nnz_ui, 70000, SHIFT1,
                                               bcur, ebin_r1, ebin_cv1);
  k_binscatter<<<gb(nnz_bi), 512, 0, stream>>>(bi_rows, bi_cols, bi_vals, nnz_bi, 220000, SHIFT1,
                                               bcur, ebin_r1, ebin_cv1);
  k_place<<<NB1, 1024, 0, stream>>>(bbase, SHIFT1, N1, ebin_r1, ebin_cv1, rptr, epack);

  auto propagate = [&](const float* A, const float* Bf, int nA, int nB,
                       const int* rp, const float* noise, float* outp) {
    int n = nA + nB;
    int tot4 = n * (DD / 4);
    k_init0<<<(tot4 + 255) / 256, 256, 0, stream>>>(A, Bf, outp, nA, n);
    int gp = (int)(((long long)n * 64 + 255) / 256);
    k_spmm_prop<<<gp, 256, 0, stream>>>(rp, epack, A, Bf, nA, noise, s2, outp, n, 1);
    k_spmm_prop<<<gp, 256, 0, stream>>>(rp, epack, s2, s2, n, noise + (size_t)n * DD,
                                        nullptr, outp, n, 0);
  };

  propagate(usersF, bundlesF, U_N, B_N, rp_ub, noise_UB, o_UB);
  propagate(usersF, itemsF, U_N, I_N, rp_ui, noise_UI, o_UI);
  propagate(bundlesF, itemsF, B_N, I_N, rp_bi, noise_BI, o_BI);

  // ---- phase-2 CSR: BIAGG rows [0,20000), UIAGG rows [20000,70000)
  int* rp_ba = rptr, * rp_ua = rptr + 20000;
  hipMemsetAsync(bcnt, 0, 512 * sizeof(int), stream);
  k_bhist<<<gb(nnz_biagg), 512, 0, stream>>>(biagg_rows, nnz_biagg, 0, SHIFT2, bcnt);
  k_bhist<<<gb(nnz_uiagg), 512, 0, stream>>>(uiagg_rows, nnz_uiagg, 20000, SHIFT2, bcnt);
  k_bucket_scan<<<1, 512, 0, stream>>>(bcnt, NB2, bbase, bcur, rptr + N2, nnzTot2);
  k_binscatter<<<gb(nnz_biagg), 512, 0, stream>>>(biagg_rows, biagg_cols, biagg_vals, nnz_biagg,
                                                  0, SHIFT2, bcur, ebin_r2, ebin_cv2);
  k_binscatter<<<gb(nnz_uiagg), 512, 0, stream>>>(uiagg_rows, uiagg_cols, uiagg_vals, nnz_uiagg,
                                                  20000, SHIFT2, bcur, ebin_r2, ebin_cv2);
  k_place<<<NB2, 1024, 0, stream>>>(bbase, SHIFT2, N2, ebin_r2, ebin_cv2, rptr, epack);

  k_spmm_agg<<<(int)(((long long)B_N * 64 + 255) / 256), 256, 0, stream>>>(
      rp_ba, epack, o_UI + (size_t)U_N * DD, noise_agg_BI, uib, B_N);
  k_spmm_agg<<<(int)(((long long)U_N * 64 + 255) / 256), 256, 0, stream>>>(
      rp_ua, epack, o_BI + (size_t)B_N * DD, noise_agg_UI, biu, U_N);

  // heads
  k_bpr<<<BATCH * 64 / 256, 256, 0, stream>>>(o_UI, biu, uib, o_BI, users, bundles, bprT);
  k_sumsq_p<<<256, 256, 0, stream>>>(usersF, U_N * DD / 4, prt);
  k_sumsq_p<<<256, 256, 0, stream>>>(bundlesF, B_N * DD / 4, prt + 256);
  k_sumsq_p<<<256, 256, 0, stream>>>(itemsF, I_N * DD / 4, prt + 512);
  k_gather<<<6 * BATCH * 64 / 256, 256, 0, stream>>>(o_UB, o_UI, o_BI, uib, biu,
                                                     users, bundles, P, Pb);
  hipMemsetAsync(ttl, 0, (size_t)12 * BATCH * sizeof(float), stream);
  k_clpair_mfma<<<768, 256, 0, stream>>>(Pb, ttl);
  k_cldiag<<<12 * BATCH * 64 / 256, 256, 0, stream>>>(P, ttl);
  k_finalred<<<1, 1024, 0, stream>>>(bprT, ttl, prt, (float*)d_out);
}

// Round 2
// 1107.853 us; speedup vs baseline: 1.5579x; 1.1766x over previous
//
#include <hip/hip_runtime.h>
#include <cmath>

#define DD 64

namespace {

constexpr int U_N = 50000, B_N = 20000, I_N = 100000;
constexpr int BATCH = 2048;

// phase-1 CSR: 340000 rows, bucket = row >> 10 (1024 rows/bucket, 333 buckets)
// phase-2 CSR: 70000 rows,  bucket = row >> 8  (256 rows/bucket, 274 buckets)
constexpr int N1 = 340000, N2 = 70000;
constexpr int SHIFT1 = 10, SHIFT2 = 8;
constexpr int NB1 = (N1 + (1 << SHIFT1) - 1) >> SHIFT1;  // 333
constexpr int NB2 = (N2 + (1 << SHIFT2) - 1) >> SHIFT2;  // 274

typedef __attribute__((ext_vector_type(8))) short short8;   // 8 bf16 (4 VGPRs)
typedef __attribute__((ext_vector_type(4))) float floatx4;  // 4 fp32 acc

__device__ __forceinline__ float wave_sum(float v) {
#pragma unroll
  for (int off = 32; off > 0; off >>= 1) v += __shfl_xor(v, off);
  return v;
}

__device__ __forceinline__ unsigned short f2bf(float f) {
  unsigned u = __float_as_uint(f);
  unsigned r = (u + 0x7FFFu + ((u >> 16) & 1u)) >> 16;  // RNE
  return (unsigned short)r;
}

__device__ __forceinline__ float sgn(float x) {
  return (x > 0.f) ? 1.f : ((x < 0.f) ? -1.f : 0.f);
}

// ---------------- CSR build (two-pass bucketed binning) ----------------
// Pass 0: coarse bucket histogram (LDS-staged). Optional sampled-row filter.
__global__ __launch_bounds__(512) void k_bhist(const int* __restrict__ rows, int nnz,
                                               int row_off, int shift,
                                               const unsigned char* __restrict__ flags,
                                               int* __restrict__ bcnt) {
  __shared__ int h[512];
  int t = threadIdx.x;
  h[t] = 0;
  __syncthreads();
  int tile0 = blockIdx.x * 8192;
#pragma unroll
  for (int i = 0; i < 16; ++i) {
    int e = tile0 + i * 512 + t;
    if (e < nnz) {
      int r = rows[e] + row_off;
      if (!flags || flags[r]) atomicAdd(&h[r >> shift], 1);
    }
  }
  __syncthreads();
  if (h[t]) atomicAdd(&bcnt[t], h[t]);
}

// single-block exclusive scan of <=512 bucket counts -> base & cursor; total computed here
__global__ void k_bucket_scan(const int* __restrict__ bcnt, int nb, int* __restrict__ bbase,
                              int* __restrict__ bcur, int* __restrict__ rowptr_end) {
  int t = threadIdx.x;  // 512
  int lane = t & 63, w = t >> 6;
  int v = (t < nb) ? bcnt[t] : 0;
  int inc = v;
#pragma unroll
  for (int off = 1; off < 64; off <<= 1) {
    int y = __shfl_up(inc, off);
    if (lane >= off) inc += y;
  }
  __shared__ int wsum[8];
  if (lane == 63) wsum[w] = inc;
  __syncthreads();
  int wadd = 0;
  for (int i = 0; i < w; ++i) wadd += wsum[i];
  inc += wadd;
  if (t < nb) { bbase[t] = inc - v; bcur[t] = inc - v; }
  if (t == 511) { bbase[nb] = inc; *rowptr_end = inc; }
}

// Pass 1: bin edges bucket-grouped; entry packs (rowlocal<<20)|col (col<2^18, rl<2^10).
__global__ __launch_bounds__(512) void k_binscatter(const int* __restrict__ rows,
                                                    const int* __restrict__ cols,
                                                    const float* __restrict__ vals, int nnz,
                                                    int row_off, int shift,
                                                    const unsigned char* __restrict__ flags,
                                                    int* __restrict__ bcur,
                                                    int2* __restrict__ ebin_cv) {
  __shared__ int cnt[512];
  __shared__ int gbase[512];
  int t = threadIdx.x;
  int tile0 = blockIdx.x * 8192;
  cnt[t] = 0;
  __syncthreads();
  int r[16], rank[16];
#pragma unroll
  for (int i = 0; i < 16; ++i) {
    int e = tile0 + i * 512 + t;
    rank[i] = -1;
    if (e < nnz) {
      r[i] = rows[e] + row_off;
      if (!flags || flags[r[i]]) rank[i] = atomicAdd(&cnt[r[i] >> shift], 1);
    }
  }
  __syncthreads();
  int c = cnt[t];
  if (c > 0) gbase[t] = atomicAdd(&bcur[t], c);
  __syncthreads();
  int mask = (1 << shift) - 1;
#pragma unroll
  for (int i = 0; i < 16; ++i) {
    int e = tile0 + i * 512 + t;
    if (rank[i] >= 0) {
      int pos = gbase[r[i] >> shift] + rank[i];
      ebin_cv[pos] = make_int2(((r[i] & mask) << 20) | cols[e], __float_as_int(vals[e]));
    }
  }
}

// Pass 2: one workgroup per bucket. LDS row-hist + in-block scan writes rowptr directly;
// then exact placement via LDS cursors. Bucket region written by one block -> full lines.
__global__ __launch_bounds__(1024) void k_place(const int* __restrict__ bbase, int shift,
                                                int nrows, const int2* __restrict__ ebin_cv,
                                                int* __restrict__ rowptr,
                                                int2* __restrict__ epack) {
  int b = blockIdx.x;
  int bsize = 1 << shift;
  int row0 = b << shift;
  int t = threadIdx.x;
  __shared__ int rcnt[1024];
  __shared__ int wsum[16];
  int ebase = bbase[b], eend = bbase[b + 1];
  if (t < bsize) rcnt[t] = 0;
  __syncthreads();
  for (int e = ebase + t; e < eend; e += 1024)
    atomicAdd(&rcnt[ebin_cv[e].x >> 20], 1);
  __syncthreads();
  int v = (t < bsize) ? rcnt[t] : 0;
  int inc = v;
  int lane = t & 63, w = t >> 6;
#pragma unroll
  for (int off = 1; off < 64; off <<= 1) {
    int y = __shfl_up(inc, off);
    if (lane >= off) inc += y;
  }
  if (lane == 63) wsum[w] = inc;
  __syncthreads();
  int wadd = 0;
  for (int i = 0; i < w; ++i) wadd += wsum[i];
  inc += wadd;
  int excl = inc - v;  // exclusive scan of per-row counts within bucket
  int nr = nrows - row0;
  if (nr > bsize) nr = bsize;
  if (t < nr) rowptr[row0 + t] = ebase + excl;
  __syncthreads();
  if (t < bsize) rcnt[t] = excl;  // reuse as cursor
  __syncthreads();
  for (int e = ebase + t; e < eend; e += 1024) {
    int2 cv = ebin_cv[e];
    int pos = ebase + atomicAdd(&rcnt[cv.x >> 20], 1);
    epack[pos] = make_int2(cv.x & 0xFFFFF, cv.y);
  }
}

// ---------------- fused gather SPMM ----------------
// layer 1: gather from two source arrays, write unnormalized noisy feats (s2) only.
__global__ void k_spmm1(const int* __restrict__ rowptr, const int2* __restrict__ epack,
                        const float* __restrict__ xA, const float* __restrict__ xB,
                        int nA, const float* __restrict__ noise,
                        float* __restrict__ s2out, int n) {
  long long t = (long long)blockIdx.x * 256 + threadIdx.x;
  int row = (int)(t >> 6), lane = (int)(t & 63);
  if (row >= n) return;
  int q = lane >> 4, c = lane & 15;
  int s = rowptr[row], e = rowptr[row + 1];
  float4 a0 = {0.f, 0.f, 0.f, 0.f}, a1 = {0.f, 0.f, 0.f, 0.f};
  float4 a2 = {0.f, 0.f, 0.f, 0.f}, a3 = {0.f, 0.f, 0.f, 0.f};
  for (int kk = s; kk < e; kk += 16) {
    int i0 = kk + q, i1 = kk + 4 + q, i2 = kk + 8 + q, i3 = kk + 12 + q;
    int2 e0 = (i0 < e) ? epack[i0] : make_int2(0, 0);
    int2 e1 = (i1 < e) ? epack[i1] : make_int2(0, 0);
    int2 e2 = (i2 < e) ? epack[i2] : make_int2(0, 0);
    int2 e3 = (i3 < e) ? epack[i3] : make_int2(0, 0);
    const float* p0 = (e0.x < nA) ? xA + (size_t)e0.x * DD : xB + (size_t)(e0.x - nA) * DD;
    const float* p1 = (e1.x < nA) ? xA + (size_t)e1.x * DD : xB + (size_t)(e1.x - nA) * DD;
    const float* p2 = (e2.x < nA) ? xA + (size_t)e2.x * DD : xB + (size_t)(e2.x - nA) * DD;
    const float* p3 = (e3.x < nA) ? xA + (size_t)e3.x * DD : xB + (size_t)(e3.x - nA) * DD;
    float4 x0 = ((const float4*)p0)[c];
    float4 x1 = ((const float4*)p1)[c];
    float4 x2 = ((const float4*)p2)[c];
    float4 x3 = ((const float4*)p3)[c];
    float v0 = __int_as_float(e0.y), v1 = __int_as_float(e1.y);
    float v2 = __int_as_float(e2.y), v3 = __int_as_float(e3.y);
    a0.x = fmaf(v0, x0.x, a0.x); a0.y = fmaf(v0, x0.y, a0.y);
    a0.z = fmaf(v0, x0.z, a0.z); a0.w = fmaf(v0, x0.w, a0.w);
    a1.x = fmaf(v1, x1.x, a1.x); a1.y = fmaf(v1, x1.y, a1.y);
    a1.z = fmaf(v1, x1.z, a1.z); a1.w = fmaf(v1, x1.w, a1.w);
    a2.x = fmaf(v2, x2.x, a2.x); a2.y = fmaf(v2, x2.y, a2.y);
    a2.z = fmaf(v2, x2.z, a2.z); a2.w = fmaf(v2, x2.w, a2.w);
    a3.x = fmaf(v3, x3.x, a3.x); a3.y = fmaf(v3, x3.y, a3.y);
    a3.z = fmaf(v3, x3.z, a3.z); a3.w = fmaf(v3, x3.w, a3.w);
  }
  float4 g;
  g.x = a0.x + a1.x + a2.x + a3.x; g.y = a0.y + a1.y + a2.y + a3.y;
  g.z = a0.z + a1.z + a2.z + a3.z; g.w = a0.w + a1.w + a2.w + a3.w;
  g.x += __shfl_xor(g.x, 16); g.y += __shfl_xor(g.y, 16);
  g.z += __shfl_xor(g.z, 16); g.w += __shfl_xor(g.w, 16);
  g.x += __shfl_xor(g.x, 32); g.y += __shfl_xor(g.y, 32);
  g.z += __shfl_xor(g.z, 32); g.w += __shfl_xor(g.w, 32);
  float4 nz = ((const float4*)(noise + (size_t)row * DD))[c];
  float nn = wave_sum(nz.x * nz.x + nz.y * nz.y + nz.z * nz.z + nz.w * nz.w) * 0.25f;
  float nf = 0.1f / fmaxf(sqrtf(nn), 1e-12f);
  if (lane < 16) {
    float4 fv;
    fv.x = g.x + sgn(g.x) * nz.x * nf;
    fv.y = g.y + sgn(g.y) * nz.y * nf;
    fv.z = g.z + sgn(g.z) * nz.z * nf;
    fv.w = g.w + sgn(g.w) * nz.w * nf;
    ((float4*)(s2out + (size_t)row * DD))[c] = fv;
  }
}

// layer 2 (fused epilogue): gather from s2, compute layer-2 noisy feats, then
// outp = x0/3 + s1*inv1 + fv2*inv2  (term0 + normalized layer1 + normalized layer2)
__global__ void k_spmm2(const int* __restrict__ rowptr, const int2* __restrict__ epack,
                        const float* __restrict__ s2, const float* __restrict__ xA,
                        const float* __restrict__ xB, int nA,
                        const float* __restrict__ noise, float* __restrict__ outp, int n) {
  long long t = (long long)blockIdx.x * 256 + threadIdx.x;
  int row = (int)(t >> 6), lane = (int)(t & 63);
  if (row >= n) return;
  int q = lane >> 4, c = lane & 15;
  int s = rowptr[row], e = rowptr[row + 1];
  float4 a0 = {0.f, 0.f, 0.f, 0.f}, a1 = {0.f, 0.f, 0.f, 0.f};
  float4 a2 = {0.f, 0.f, 0.f, 0.f}, a3 = {0.f, 0.f, 0.f, 0.f};
  for (int kk = s; kk < e; kk += 16) {
    int i0 = kk + q, i1 = kk + 4 + q, i2 = kk + 8 + q, i3 = kk + 12 + q;
    int2 e0 = (i0 < e) ? epack[i0] : make_int2(0, 0);
    int2 e1 = (i1 < e) ? epack[i1] : make_int2(0, 0);
    int2 e2 = (i2 < e) ? epack[i2] : make_int2(0, 0);
    int2 e3 = (i3 < e) ? epack[i3] : make_int2(0, 0);
    float4 x0 = ((const float4*)(s2 + (size_t)e0.x * DD))[c];
    float4 x1 = ((const float4*)(s2 + (size_t)e1.x * DD))[c];
    float4 x2 = ((const float4*)(s2 + (size_t)e2.x * DD))[c];
    float4 x3 = ((const float4*)(s2 + (size_t)e3.x * DD))[c];
    float v0 = __int_as_float(e0.y), v1 = __int_as_float(e1.y);
    float v2 = __int_as_float(e2.y), v3 = __int_as_float(e3.y);
    a0.x = fmaf(v0, x0.x, a0.x); a0.y = fmaf(v0, x0.y, a0.y);
    a0.z = fmaf(v0, x0.z, a0.z); a0.w = fmaf(v0, x0.w, a0.w);
    a1.x = fmaf(v1, x1.x, a1.x); a1.y = fmaf(v1, x1.y, a1.y);
    a1.z = fmaf(v1, x1.z, a1.z); a1.w = fmaf(v1, x1.w, a1.w);
    a2.x = fmaf(v2, x2.x, a2.x); a2.y = fmaf(v2, x2.y, a2.y);
    a2.z = fmaf(v2, x2.z, a2.z); a2.w = fmaf(v2, x2.w, a2.w);
    a3.x = fmaf(v3, x3.x, a3.x); a3.y = fmaf(v3, x3.y, a3.y);
    a3.z = fmaf(v3, x3.z, a3.z); a3.w = fmaf(v3, x3.w, a3.w);
  }
  float4 g;
  g.x = a0.x + a1.x + a2.x + a3.x; g.y = a0.y + a1.y + a2.y + a3.y;
  g.z = a0.z + a1.z + a2.z + a3.z; g.w = a0.w + a1.w + a2.w + a3.w;
  g.x += __shfl_xor(g.x, 16); g.y += __shfl_xor(g.y, 16);
  g.z += __shfl_xor(g.z, 16); g.w += __shfl_xor(g.w, 16);
  g.x += __shfl_xor(g.x, 32); g.y += __shfl_xor(g.y, 32);
  g.z += __shfl_xor(g.z, 32); g.w += __shfl_xor(g.w, 32);
  float4 nz = ((const float4*)(noise + (size_t)row * DD))[c];
  float nn = wave_sum(nz.x * nz.x + nz.y * nz.y + nz.z * nz.z + nz.w * nz.w) * 0.25f;
  float nf = 0.1f / fmaxf(sqrtf(nn), 1e-12f);
  float4 fv;
  fv.x = g.x + sgn(g.x) * nz.x * nf;
  fv.y = g.y + sgn(g.y) * nz.y * nf;
  fv.z = g.z + sgn(g.z) * nz.z * nf;
  fv.w = g.w + sgn(g.w) * nz.w * nf;
  float fn2 = wave_sum(fv.x * fv.x + fv.y * fv.y + fv.z * fv.z + fv.w * fv.w) * 0.25f;
  float inv2 = (1.f / 3.f) / fmaxf(sqrtf(fn2), 1e-12f);
  // layer-1 own row + its norm (recomputed)
  float4 s1 = ((const float4*)(s2 + (size_t)row * DD))[c];
  float fn1 = wave_sum(s1.x * s1.x + s1.y * s1.y + s1.z * s1.z + s1.w * s1.w) * 0.25f;
  float inv1 = (1.f / 3.f) / fmaxf(sqrtf(fn1), 1e-12f);
  const float* px = (row < nA) ? xA + (size_t)row * DD : xB + (size_t)(row - nA) * DD;
  float4 x0 = ((const float4*)px)[c];
  if (lane < 16) {
    float4 o;
    o.x = x0.x * (1.f / 3.f) + s1.x * inv1 + fv.x * inv2;
    o.y = x0.y * (1.f / 3.f) + s1.y * inv1 + fv.y * inv2;
    o.z = x0.z * (1.f / 3.f) + s1.z * inv1 + fv.z * inv2;
    o.w = x0.w * (1.f / 3.f) + s1.w * inv1 + fv.w * inv2;
    ((float4*)(outp + (size_t)row * DD))[c] = o;
  }
}

// sampled aggregation: one wave per sample id; out[w] = agg row ids[w]
__global__ void k_agg_s(const int* __restrict__ rowptr, const int2* __restrict__ epack,
                        const float* __restrict__ x, const float* __restrict__ noise,
                        const int* __restrict__ ids, int nids, float* __restrict__ out) {
  long long t = (long long)blockIdx.x * 256 + threadIdx.x;
  int w = (int)(t >> 6), lane = (int)(t & 63);
  if (w >= nids) return;
  int row = ids[w];
  int q = lane >> 4, c = lane & 15;
  int s = rowptr[row], e = rowptr[row + 1];
  float4 a0 = {0.f, 0.f, 0.f, 0.f}, a1 = {0.f, 0.f, 0.f, 0.f};
  for (int kk = s; kk < e; kk += 8) {
    int i0 = kk + q, i1 = kk + 4 + q;
    int2 e0 = (i0 < e) ? epack[i0] : make_int2(0, 0);
    int2 e1 = (i1 < e) ? epack[i1] : make_int2(0, 0);
    float4 x0 = ((const float4*)(x + (size_t)e0.x * DD))[c];
    float4 x1 = ((const float4*)(x + (size_t)e1.x * DD))[c];
    float v0 = __int_as_float(e0.y), v1 = __int_as_float(e1.y);
    a0.x = fmaf(v0, x0.x, a0.x); a0.y = fmaf(v0, x0.y, a0.y);
    a0.z = fmaf(v0, x0.z, a0.z); a0.w = fmaf(v0, x0.w, a0.w);
    a1.x = fmaf(v1, x1.x, a1.x); a1.y = fmaf(v1, x1.y, a1.y);
    a1.z = fmaf(v1, x1.z, a1.z); a1.w = fmaf(v1, x1.w, a1.w);
  }
  float4 g;
  g.x = a0.x + a1.x; g.y = a0.y + a1.y; g.z = a0.z + a1.z; g.w = a0.w + a1.w;
  g.x += __shfl_xor(g.x, 16); g.y += __shfl_xor(g.y, 16);
  g.z += __shfl_xor(g.z, 16); g.w += __shfl_xor(g.w, 16);
  g.x += __shfl_xor(g.x, 32); g.y += __shfl_xor(g.y, 32);
  g.z += __shfl_xor(g.z, 32); g.w += __shfl_xor(g.w, 32);
  float4 nz = ((const float4*)(noise + (size_t)row * DD))[c];
  float nn = wave_sum(nz.x * nz.x + nz.y * nz.y + nz.z * nz.z + nz.w * nz.w) * 0.25f;
  float nf = 0.1f / fmaxf(sqrtf(nn), 1e-12f);
  if (lane < 16) {
    float4 fv;
    fv.x = g.x + sgn(g.x) * nz.x * nf;
    fv.y = g.y + sgn(g.y) * nz.y * nf;
    fv.z = g.z + sgn(g.z) * nz.z * nf;
    fv.w = g.w + sgn(g.w) * nz.w * nf;
    ((float4*)(out + (size_t)w * DD))[c] = fv;
  }
}

// set sampled-row flags for phase-2 filtering (biagg rows [0,20000), uiagg [20000,70000))
__global__ void k_flag(const int* __restrict__ users, const int* __restrict__ bundles,
                       unsigned char* __restrict__ flags) {
  int t = blockIdx.x * 256 + threadIdx.x;
  if (t < BATCH) flags[20000 + users[t]] = 1;
  if (t < 2 * BATCH) flags[bundles[t]] = 1;
}

// ---------------- heads ----------------

__global__ void k_bpr(const float* __restrict__ o_UI, const float* __restrict__ biuS,
                      const float* __restrict__ uibS, const float* __restrict__ o_BI,
                      const int* __restrict__ users, const int* __restrict__ bundles,
                      float* __restrict__ bpr_terms) {
  long long t = (long long)blockIdx.x * 256 + threadIdx.x;
  int w = (int)(t >> 6);
  int lane = (int)(t & 63);
  if (w >= BATCH) return;
  int u = users[w];
  int b0 = bundles[2 * w], b1 = bundles[2 * w + 1];
  float ur = 0.5f * (o_UI[(size_t)u * DD + lane] + biuS[(size_t)w * DD + lane]);
  float br0 = 0.5f * (uibS[(size_t)(2 * w) * DD + lane] + o_BI[(size_t)b0 * DD + lane]);
  float br1 = 0.5f * (uibS[(size_t)(2 * w + 1) * DD + lane] + o_BI[(size_t)b1 * DD + lane]);
  float pos = wave_sum(ur * br0);
  float neg = wave_sum(ur * br1);
  if (lane == 0) {
    float x = pos - neg;
    float loss = (x > 0.f) ? log1pf(expf(-x)) : (-x + log1pf(expf(x)));
    bpr_terms[w] = loss;
  }
}

__global__ void k_sumsq_p(const float* __restrict__ x, int n4, float* __restrict__ partials) {
  float s = 0.f;
  for (int i = blockIdx.x * 256 + threadIdx.x; i < n4; i += gridDim.x * 256) {
    float4 v = ((const float4*)x)[i];
    s += v.x * v.x + v.y * v.y + v.z * v.z + v.w * v.w;
  }
  s = wave_sum(s);
  __shared__ float part[4];
  if ((threadIdx.x & 63) == 0) part[threadIdx.x >> 6] = s;
  __syncthreads();
  if (threadIdx.x == 0) partials[blockIdx.x] = part[0] + part[1] + part[2] + part[3];
}

// build 6 normalized (2048 x 64) matrices, fp32 + bf16 copies
__global__ void k_gather(const float* __restrict__ o_UB, const float* __restrict__ o_UI,
                         const float* __restrict__ o_BI, const float* __restrict__ uibS,
                         const float* __restrict__ biuS, const int* __restrict__ users,
                         const int* __restrict__ bundles, float* __restrict__ P,
                         unsigned short* __restrict__ Pb) {
  long long t = (long long)blockIdx.x * 256 + threadIdx.x;
  int w = (int)(t >> 6);
  int lane = (int)(t & 63);
  if (w >= 6 * BATCH) return;
  int k = w / BATCH, b = w % BATCH;
  const float* src;
  if (k == 0)      src = o_UB + (size_t)users[b] * DD;
  else if (k == 1) src = o_UI + (size_t)users[b] * DD;
  else if (k == 2) src = biuS + (size_t)b * DD;
  else if (k == 3) src = o_UB + (size_t)(U_N + bundles[2 * b]) * DD;
  else if (k == 4) src = uibS + (size_t)(2 * b) * DD;
  else             src = o_BI + (size_t)bundles[2 * b] * DD;
  float v = src[lane];
  float n2 = wave_sum(v * v);
  float inv = 1.f / fmaxf(sqrtf(n2), 1e-12f);
  float pv = v * inv;
  P[(size_t)w * DD + lane] = pv;
  Pb[(size_t)w * DD + lane] = f2bf(pv);
}

// MFMA CL pair kernel: each wave computes a 64x256 S-chunk of one pair,
// ttl[p][i] += sum_j exp(4 * X_i . Y_j)   (atomic partial row-sums)
__global__ void k_clpair_mfma(const unsigned short* __restrict__ Pb,
                              float* __restrict__ ttl) {
  const int pairX[12] = {0, 0, 1, 0, 1, 2, 3, 3, 4, 3, 4, 5};
  const int pairY[12] = {1, 2, 2, 0, 1, 2, 4, 5, 5, 3, 4, 5};
  int wid = threadIdx.x >> 6;
  int lane = threadIdx.x & 63;
  int wtile = blockIdx.x * 4 + wid;     // 12 * 32 * 8 = 3072 wave-tiles
  int p = wtile >> 8;                   // / 256
  int rest = wtile & 255;
  int it = rest >> 3, jc = rest & 7;    // 64-row i-tile, 256-col j-chunk
  const unsigned short* X = Pb + (size_t)pairX[p] * BATCH * DD;
  const unsigned short* Y = Pb + (size_t)pairY[p] * BATCH * DD;
  int r = lane & 15, q = lane >> 4;
  short8 A[2][4];
#pragma unroll
  for (int kh = 0; kh < 2; ++kh)
#pragma unroll
    for (int ii = 0; ii < 4; ++ii)
      A[kh][ii] = *(const short8*)(X + (size_t)(it * 64 + ii * 16 + r) * DD + kh * 32 + q * 8);
  float rs[4][4];  // [ii][reg] row-sums of exp
#pragma unroll
  for (int ii = 0; ii < 4; ++ii)
#pragma unroll
    for (int g = 0; g < 4; ++g) rs[ii][g] = 0.f;
  for (int jn = 0; jn < 4; ++jn) {
    int j0 = jc * 256 + jn * 64;
    floatx4 acc[4][4];
#pragma unroll
    for (int ii = 0; ii < 4; ++ii)
#pragma unroll
      for (int jj = 0; jj < 4; ++jj) acc[ii][jj] = (floatx4){0.f, 0.f, 0.f, 0.f};
#pragma unroll
    for (int kh = 0; kh < 2; ++kh) {
      short8 Bf[4];
#pragma unroll
      for (int jj = 0; jj < 4; ++jj)
        Bf[jj] = *(const short8*)(Y + (size_t)(j0 + jj * 16 + r) * DD + kh * 32 + q * 8);
#pragma unroll
      for (int ii = 0; ii < 4; ++ii)
#pragma unroll
        for (int jj = 0; jj < 4; ++jj)
          acc[ii][jj] = __builtin_amdgcn_mfma_f32_16x16x32_bf16(A[kh][ii], Bf[jj],
                                                                acc[ii][jj], 0, 0, 0);
    }
#pragma unroll
    for (int ii = 0; ii < 4; ++ii)
#pragma unroll
      for (int jj = 0; jj < 4; ++jj)
#pragma unroll
        for (int g = 0; g < 4; ++g) rs[ii][g] += __expf(4.0f * acc[ii][jj][g]);
  }
#pragma unroll
  for (int off = 1; off < 16; off <<= 1)
#pragma unroll
    for (int ii = 0; ii < 4; ++ii)
#pragma unroll
      for (int g = 0; g < 4; ++g) rs[ii][g] += __shfl_xor(rs[ii][g], off);
  if (r == 0) {
#pragma unroll
    for (int ii = 0; ii < 4; ++ii)
#pragma unroll
      for (int g = 0; g < 4; ++g)
        unsafeAtomicAdd(&ttl[(size_t)p * BATCH + it * 64 + ii * 16 + q * 4 + g],
                        rs[ii][g]);
  }
}

// per (pair, i): ttl[p,i] <- log(ttl[p,i]) - diag/tau  (diag in fp32)
__global__ void k_cldiag(const float* __restrict__ P, float* __restrict__ ttl) {
  const int pairX[12] = {0, 0, 1, 0, 1, 2, 3, 3, 4, 3, 4, 5};
  const int pairY[12] = {1, 2, 2, 0, 1, 2, 4, 5, 5, 3, 4, 5};
  long long t = (long long)blockIdx.x * 256 + threadIdx.x;
  int w = (int)(t >> 6);
  int lane = (int)(t & 63);
  if (w >= 12 * BATCH) return;
  int p = w / BATCH, i = w % BATCH;
  float xv = P[((size_t)pairX[p] * BATCH + i) * DD + lane];
  float yv = P[((size_t)pairY[p] * BATCH + i) * DD + lane];
  float d = wave_sum(xv * yv);
  if (lane == 0) ttl[(size_t)p * BATCH + i] = logf(ttl[(size_t)p * BATCH + i]) - d * 4.0f;
}

__global__ void k_finalred(const float* __restrict__ bpr_terms,
                           const float* __restrict__ cl_terms,
                           const float* __restrict__ partials,
                           float* __restrict__ out) {
  int t = threadIdx.x;  // 1024
  float bpr = 0.f, reg = 0.f, inter = 0.f, intra = 0.f;
  for (int i = t; i < BATCH; i += 1024) bpr += bpr_terms[i];
  for (int i = t; i < 768; i += 1024) reg += partials[i];
  for (int i = t; i < 12 * BATCH; i += 1024) {
    int p = i >> 11;
    float v = cl_terms[i];
    if ((p % 6) < 3) inter += v; else intra += v;
  }
  bpr = wave_sum(bpr); reg = wave_sum(reg);
  inter = wave_sum(inter); intra = wave_sum(intra);
  __shared__ float sb[16], sr[16], si[16], sx[16];
  int w = t >> 6, lane = t & 63;
  if (lane == 0) { sb[w] = bpr; sr[w] = reg; si[w] = inter; sx[w] = intra; }
  __syncthreads();
  if (t == 0) {
    float Bs = 0, Rs = 0, Is = 0, Xs = 0;
    for (int i = 0; i < 16; ++i) { Bs += sb[i]; Rs += sr[i]; Is += si[i]; Xs += sx[i]; }
    out[0] = Bs / (float)BATCH + 1e-5f * Rs;
    out[1] = 0.04f * (0.5f * Is + 0.5f * Xs) / (float)BATCH;
  }
}

}  // namespace

extern "C" void kernel_launch(void* const* d_in, const int* in_sizes, int n_in,
                              void* d_out, int out_size, void* d_ws, size_t ws_size,
                              hipStream_t stream) {
  const float* usersF = (const float*)d_in[0];
  const float* bundlesF = (const float*)d_in[1];
  const float* itemsF = (const float*)d_in[2];
  const int* ub_rows = (const int*)d_in[3];
  const int* ub_cols = (const int*)d_in[4];
  const float* ub_vals = (const float*)d_in[5];
  const int* ui_rows = (const int*)d_in[6];
  const int* ui_cols = (const int*)d_in[7];
  const float* ui_vals = (const float*)d_in[8];
  const int* bi_rows = (const int*)d_in[9];
  const int* bi_cols = (const int*)d_in[10];
  const float* bi_vals = (const float*)d_in[11];
  const int* biagg_rows = (const int*)d_in[12];
  const int* biagg_cols = (const int*)d_in[13];
  const float* biagg_vals = (const float*)d_in[14];
  const int* uiagg_rows = (const int*)d_in[15];
  const int* uiagg_cols = (const int*)d_in[16];
  const float* uiagg_vals = (const float*)d_in[17];
  const float* noise_UB = (const float*)d_in[18];
  const float* noise_UI = (const float*)d_in[19];
  const float* noise_BI = (const float*)d_in[20];
  const float* noise_agg_BI = (const float*)d_in[21];
  const float* noise_agg_UI = (const float*)d_in[22];
  const int* users = (const int*)d_in[23];
  const int* bundles = (const int*)d_in[24];
  int nnz_ub = in_sizes[3], nnz_ui = in_sizes[6], nnz_bi = in_sizes[9];
  int nnz_biagg = in_sizes[12], nnz_uiagg = in_sizes[15];
  int nnzTot1 = nnz_ub + nnz_ui + nnz_bi;
  int nnzTot2 = nnz_biagg + nnz_uiagg;

  float* ws = (float*)d_ws;
  size_t off = 0;
  float* o_UB = ws + off; off += (size_t)(U_N + B_N) * DD;
  float* o_UI = ws + off; off += (size_t)(U_N + I_N) * DD;
  float* o_BI = ws + off; off += (size_t)(B_N + I_N) * DD;
  float* uibS = ws + off; off += (size_t)2 * BATCH * DD;   // rows bundles[j], j in [0,4096)
  float* biuS = ws + off; off += (size_t)BATCH * DD;       // rows users[w]
  float* s2   = ws + off; off += (size_t)(U_N + I_N) * DD;
  float* P    = ws + off; off += (size_t)6 * BATCH * DD;
  float* ttl  = ws + off; off += (size_t)12 * BATCH;
  float* bprT = ws + off; off += BATCH;
  float* prt  = ws + off; off += 768;
  // Pb (bf16 copy of P) aliases s2: s2 is dead after the last spmm2
  unsigned short* Pb = (unsigned short*)s2;
  int* rptr  = (int*)(ws + off); off += N1 + 1;
  int* bcnt  = (int*)(ws + off); off += 512;
  int* bbase = (int*)(ws + off); off += 520;
  int* bcur  = (int*)(ws + off); off += 512;
  unsigned char* flags = (unsigned char*)(ws + off); off += 17500;  // 70000 B
  off = (off + 1) & ~(size_t)1;  // 8B align
  int2* epack = (int2*)(ws + off); off += (size_t)5200000 * 2;
  if (ws_size < off * sizeof(float)) return;  // insufficient workspace

  // binning staging buffers alias dead regions:
  // phase 1 (before any propagate): o_UB/o_UI region (14.1M floats >= 10.4M needed)
  int2* ebin_cv1 = (int2*)ws;
  // phase 2 (after propagates, s2 dead): s2 region (9.6M floats >= needed)
  int2* ebin_cv2 = (int2*)s2;

  auto gb = [](int nnz) { return (nnz + 8191) / 8192; };

  // ---- phase-1 CSR: UB rows [0,70000), UI rows [70000,220000), BI rows [220000,340000)
  int* rp_ub = rptr, * rp_ui = rptr + 70000, * rp_bi = rptr + 220000;
  hipMemsetAsync(bcnt, 0, 512 * sizeof(int), stream);
  k_bhist<<<gb(nnz_ub), 512, 0, stream>>>(ub_rows, nnz_ub, 0, SHIFT1, nullptr, bcnt);
  k_bhist<<<gb(nnz_ui), 512, 0, stream>>>(ui_rows, nnz_ui, 70000, SHIFT1, nullptr, bcnt);
  k_bhist<<<gb(nnz_bi), 512, 0, stream>>>(bi_rows, nnz_bi, 220000, SHIFT1, nullptr, bcnt);
  k_bucket_scan<<<1, 512, 0, stream>>>(bcnt, NB1, bbase, bcur, rptr + N1);
  k_binscatter<<<gb(nnz_ub), 512, 0, stream>>>(ub_rows, ub_cols, ub_vals, nnz_ub, 0, SHIFT1,
                                               nullptr, bcur, ebin_cv1);
  k_binscatter<<<gb(nnz_ui), 512, 0, stream>>>(ui_rows, ui_cols, ui_vals, nnz_ui, 70000, SHIFT1,
                                               nullptr, bcur, ebin_cv1);
  k_binscatter<<<gb(nnz_bi), 512, 0, stream>>>(bi_rows, bi_cols, bi_vals, nnz_bi, 220000, SHIFT1,
                                               nullptr, bcur, ebin_cv1);
  k_place<<<NB1, 1024, 0, stream>>>(bbase, SHIFT1, N1, ebin_cv1, rptr, epack);

  auto propagate = [&](const float* A, const float* Bf, int nA, int nB,
                       const int* rp, const float* noise, float* outp) {
    int n = nA + nB;
    int gp = (int)(((long long)n * 64 + 255) / 256);
    k_spmm1<<<gp, 256, 0, stream>>>(rp, epack, A, Bf, nA, noise, s2, n);
    k_spmm2<<<gp, 256, 0, stream>>>(rp, epack, s2, A, Bf, nA, noise + (size_t)n * DD,
                                    outp, n);
  };

  propagate(usersF, bundlesF, U_N, B_N, rp_ub, noise_UB, o_UB);
  propagate(usersF, itemsF, U_N, I_N, rp_ui, noise_UI, o_UI);
  propagate(bundlesF, itemsF, B_N, I_N, rp_bi, noise_BI, o_BI);

  // ---- phase-2 CSR (sampled-row filtered): BIAGG rows [0,20000), UIAGG rows [20000,70000)
  int* rp_ba = rptr, * rp_ua = rptr + 20000;
  hipMemsetAsync(flags, 0, 70000, stream);
  k_flag<<<(2 * BATCH + 255) / 256, 256, 0, stream>>>(users, bundles, flags);
  hipMemsetAsync(bcnt, 0, 512 * sizeof(int), stream);
  k_bhist<<<gb(nnz_biagg), 512, 0, stream>>>(biagg_rows, nnz_biagg, 0, SHIFT2, flags, bcnt);
  k_bhist<<<gb(nnz_uiagg), 512, 0, stream>>>(uiagg_rows, nnz_uiagg, 20000, SHIFT2, flags, bcnt);
  k_bucket_scan<<<1, 512, 0, stream>>>(bcnt, NB2, bbase, bcur, rptr + N2);
  k_binscatter<<<gb(nnz_biagg), 512, 0, stream>>>(biagg_rows, biagg_cols, biagg_vals, nnz_biagg,
                                                  0, SHIFT2, flags, bcur, ebin_cv2);
  k_binscatter<<<gb(nnz_uiagg), 512, 0, stream>>>(uiagg_rows, uiagg_cols, uiagg_vals, nnz_uiagg,
                                                  20000, SHIFT2, flags, bcur, ebin_cv2);
  k_place<<<NB2, 1024, 0, stream>>>(bbase, SHIFT2, N2, ebin_cv2, rptr, epack);

  // sampled aggregations (only the rows the heads read)
  k_agg_s<<<(2 * BATCH * 64) / 256, 256, 0, stream>>>(
      rp_ba, epack, o_UI + (size_t)U_N * DD, noise_agg_BI, bundles, 2 * BATCH, uibS);
  k_agg_s<<<(BATCH * 64) / 256, 256, 0, stream>>>(
      rp_ua, epack, o_BI + (size_t)B_N * DD, noise_agg_UI, users, BATCH, biuS);

  // heads
  k_bpr<<<BATCH * 64 / 256, 256, 0, stream>>>(o_UI, biuS, uibS, o_BI, users, bundles, bprT);
  k_sumsq_p<<<256, 256, 0, stream>>>(usersF, U_N * DD / 4, prt);
  k_sumsq_p<<<256, 256, 0, stream>>>(bundlesF, B_N * DD / 4, prt + 256);
  k_sumsq_p<<<256, 256, 0, stream>>>(itemsF, I_N * DD / 4, prt + 512);
  k_gather<<<6 * BATCH * 64 / 256, 256, 0, stream>>>(o_UB, o_UI, o_BI, uibS, biuS,
                                                     users, bundles, P, Pb);
  hipMemsetAsync(ttl, 0, (size_t)12 * BATCH * sizeof(float), stream);
  k_clpair_mfma<<<768, 256, 0, stream>>>(Pb, ttl);
  k_cldiag<<<12 * BATCH * 64 / 256, 256, 0, stream>>>(P, ttl);
  k_finalred<<<1, 1024, 0, stream>>>(bprT, ttl, prt, (float*)d_out);
}

// Round 3
// 1065.293 us; speedup vs baseline: 1.6201x; 1.0400x over previous
//
#include <hip/hip_runtime.h>
#include <cmath>
#include <climits>

#define DD 64

namespace {

constexpr int U_N = 50000, B_N = 20000, I_N = 100000;
constexpr int BATCH = 2048;

// phase-1 CSR: 340000 rows, bucket = row >> 10 (1024 rows/bucket, 333 buckets)
// phase-2 CSR: 70000 rows,  bucket = row >> 8  (256 rows/bucket, 274 buckets)
constexpr int N1 = 340000, N2 = 70000;
constexpr int SHIFT1 = 10, SHIFT2 = 8;
constexpr int NB1 = (N1 + (1 << SHIFT1) - 1) >> SHIFT1;  // 333
constexpr int NB2 = (N2 + (1 << SHIFT2) - 1) >> SHIFT2;  // 274

typedef __attribute__((ext_vector_type(8))) short short8;   // 8 bf16 (4 VGPRs)
typedef __attribute__((ext_vector_type(4))) float floatx4;  // 4 fp32 acc

__device__ __forceinline__ float wave_sum(float v) {
#pragma unroll
  for (int off = 32; off > 0; off >>= 1) v += __shfl_xor(v, off);
  return v;
}

__device__ __forceinline__ unsigned short f2bf(float f) {
  unsigned u = __float_as_uint(f);
  unsigned r = (u + 0x7FFFu + ((u >> 16) & 1u)) >> 16;  // RNE
  return (unsigned short)r;
}

__device__ __forceinline__ float sgn(float x) {
  return (x > 0.f) ? 1.f : ((x < 0.f) ? -1.f : 0.f);
}

// fp32 row-major -> bf16 (packed), 4 elems/thread
__global__ void k_tobf16(const float* __restrict__ x, unsigned short* __restrict__ o, int n4) {
  int i = blockIdx.x * 256 + threadIdx.x;
  if (i >= n4) return;
  float4 v = ((const float4*)x)[i];
  uint2 p;
  p.x = (unsigned)f2bf(v.x) | ((unsigned)f2bf(v.y) << 16);
  p.y = (unsigned)f2bf(v.z) | ((unsigned)f2bf(v.w) << 16);
  ((uint2*)o)[i] = p;
}

// ---------------- CSR build (two-pass bucketed binning) ----------------
// Pass 0: coarse bucket histogram (LDS-staged). Optional sampled-row filter.
__global__ __launch_bounds__(512) void k_bhist(const int* __restrict__ rows, int nnz,
                                               int row_off, int shift,
                                               const unsigned char* __restrict__ flags,
                                               int* __restrict__ bcnt) {
  __shared__ int h[512];
  int t = threadIdx.x;
  h[t] = 0;
  __syncthreads();
  int tile0 = blockIdx.x * 8192;
#pragma unroll
  for (int i = 0; i < 16; ++i) {
    int e = tile0 + i * 512 + t;
    if (e < nnz) {
      int r = rows[e] + row_off;
      if (!flags || flags[r]) atomicAdd(&h[r >> shift], 1);
    }
  }
  __syncthreads();
  if (h[t]) atomicAdd(&bcnt[t], h[t]);
}

// single-block exclusive scan of <=512 bucket counts -> base & cursor
__global__ void k_bucket_scan(const int* __restrict__ bcnt, int nb, int* __restrict__ bbase,
                              int* __restrict__ bcur, int* __restrict__ rowptr_end) {
  int t = threadIdx.x;  // 512
  int lane = t & 63, w = t >> 6;
  int v = (t < nb) ? bcnt[t] : 0;
  int inc = v;
#pragma unroll
  for (int off = 1; off < 64; off <<= 1) {
    int y = __shfl_up(inc, off);
    if (lane >= off) inc += y;
  }
  __shared__ int wsum[8];
  if (lane == 63) wsum[w] = inc;
  __syncthreads();
  int wadd = 0;
  for (int i = 0; i < w; ++i) wadd += wsum[i];
  inc += wadd;
  if (t < nb) { bbase[t] = inc - v; bcur[t] = inc - v; }
  if (t == 511) { bbase[nb] = inc; *rowptr_end = inc; }
}

// Pass 1: bin edges bucket-grouped; entry packs (rowlocal<<20)|globalcol (col<2^18).
// Column remap to concatenated global node space folded in here:
//   gcol = col < nAth ? col + offA : col + offB
__global__ __launch_bounds__(512) void k_binscatter(const int* __restrict__ rows,
                                                    const int* __restrict__ cols,
                                                    const float* __restrict__ vals, int nnz,
                                                    int row_off, int shift,
                                                    int nAth, int offA, int offB,
                                                    const unsigned char* __restrict__ flags,
                                                    int* __restrict__ bcur,
                                                    int2* __restrict__ ebin_cv) {
  __shared__ int cnt[512];
  __shared__ int gbase[512];
  int t = threadIdx.x;
  int tile0 = blockIdx.x * 8192;
  cnt[t] = 0;
  __syncthreads();
  int r[16], rank[16];
#pragma unroll
  for (int i = 0; i < 16; ++i) {
    int e = tile0 + i * 512 + t;
    rank[i] = -1;
    if (e < nnz) {
      r[i] = rows[e] + row_off;
      if (!flags || flags[r[i]]) rank[i] = atomicAdd(&cnt[r[i] >> shift], 1);
    }
  }
  __syncthreads();
  int c = cnt[t];
  if (c > 0) gbase[t] = atomicAdd(&bcur[t], c);
  __syncthreads();
  int mask = (1 << shift) - 1;
#pragma unroll
  for (int i = 0; i < 16; ++i) {
    int e = tile0 + i * 512 + t;
    if (rank[i] >= 0) {
      int pos = gbase[r[i] >> shift] + rank[i];
      int col = cols[e];
      int gcol = (col < nAth) ? col + offA : col + offB;
      ebin_cv[pos] = make_int2(((r[i] & mask) << 20) | gcol, __float_as_int(vals[e]));
    }
  }
}

// Pass 2: one workgroup per bucket. LDS row-hist + in-block scan writes rowptr directly;
// then exact placement via LDS cursors. Bucket region written by one block -> full lines.
__global__ __launch_bounds__(1024) void k_place(const int* __restrict__ bbase, int shift,
                                                int nrows, const int2* __restrict__ ebin_cv,
                                                int* __restrict__ rowptr,
                                                int2* __restrict__ epack) {
  int b = blockIdx.x;
  int bsize = 1 << shift;
  int row0 = b << shift;
  int t = threadIdx.x;
  __shared__ int rcnt[1024];
  __shared__ int wsum[16];
  int ebase = bbase[b], eend = bbase[b + 1];
  if (t < bsize) rcnt[t] = 0;
  __syncthreads();
  for (int e = ebase + t; e < eend; e += 1024)
    atomicAdd(&rcnt[ebin_cv[e].x >> 20], 1);
  __syncthreads();
  int v = (t < bsize) ? rcnt[t] : 0;
  int inc = v;
  int lane = t & 63, w = t >> 6;
#pragma unroll
  for (int off = 1; off < 64; off <<= 1) {
    int y = __shfl_up(inc, off);
    if (lane >= off) inc += y;
  }
  if (lane == 63) wsum[w] = inc;
  __syncthreads();
  int wadd = 0;
  for (int i = 0; i < w; ++i) wadd += wsum[i];
  inc += wadd;
  int excl = inc - v;  // exclusive scan of per-row counts within bucket
  int nr = nrows - row0;
  if (nr > bsize) nr = bsize;
  if (t < nr) rowptr[row0 + t] = ebase + excl;
  __syncthreads();
  if (t < bsize) rcnt[t] = excl;  // reuse as cursor
  __syncthreads();
  for (int e = ebase + t; e < eend; e += 1024) {
    int2 cv = ebin_cv[e];
    int pos = ebase + atomicAdd(&rcnt[cv.x >> 20], 1);
    epack[pos] = make_int2(cv.x & 0xFFFFF, cv.y);
  }
}

// ---------------- fused gather SPMM (bf16 feature streams) ----------------
// bf16 row = 128 B = 16 x uint2; lane c in [0,16) holds elems [4c,4c+4).
// Layer 1: gather bf16 global features, write bf16 noisy layer-1 feats (global layout).
__global__ void k_spmm1(const int* __restrict__ rowptr, const int2* __restrict__ epack,
                        const uint2* __restrict__ xg, const float* __restrict__ noise,
                        uint2* __restrict__ s2g, int n, int nAth, int offA, int offB) {
  long long t = (long long)blockIdx.x * 256 + threadIdx.x;
  int row = (int)(t >> 6), lane = (int)(t & 63);
  if (row >= n) return;
  int q = lane >> 4, c = lane & 15;
  int s = rowptr[row], e = rowptr[row + 1];
  float4 a[4];
#pragma unroll
  for (int j = 0; j < 4; ++j) a[j] = (float4){0.f, 0.f, 0.f, 0.f};
  for (int kk = s; kk < e; kk += 16) {
#pragma unroll
    for (int j = 0; j < 4; ++j) {
      int i = kk + 4 * j + q;
      int2 ed = (i < e) ? epack[i] : make_int2(0, 0);
      uint2 d = xg[ed.x * 16 + c];
      float v = __int_as_float(ed.y);
      a[j].x = fmaf(v, __uint_as_float(d.x << 16), a[j].x);
      a[j].y = fmaf(v, __uint_as_float(d.x & 0xffff0000u), a[j].y);
      a[j].z = fmaf(v, __uint_as_float(d.y << 16), a[j].z);
      a[j].w = fmaf(v, __uint_as_float(d.y & 0xffff0000u), a[j].w);
    }
  }
  float4 g;
  g.x = a[0].x + a[1].x + a[2].x + a[3].x;
  g.y = a[0].y + a[1].y + a[2].y + a[3].y;
  g.z = a[0].z + a[1].z + a[2].z + a[3].z;
  g.w = a[0].w + a[1].w + a[2].w + a[3].w;
  g.x += __shfl_xor(g.x, 16); g.y += __shfl_xor(g.y, 16);
  g.z += __shfl_xor(g.z, 16); g.w += __shfl_xor(g.w, 16);
  g.x += __shfl_xor(g.x, 32); g.y += __shfl_xor(g.y, 32);
  g.z += __shfl_xor(g.z, 32); g.w += __shfl_xor(g.w, 32);
  float4 nz = ((const float4*)(noise + (size_t)row * DD))[c];
  float nn = wave_sum(nz.x * nz.x + nz.y * nz.y + nz.z * nz.z + nz.w * nz.w) * 0.25f;
  float nf = 0.1f / fmaxf(sqrtf(nn), 1e-12f);
  if (lane < 16) {
    float4 fv;
    fv.x = g.x + sgn(g.x) * nz.x * nf;
    fv.y = g.y + sgn(g.y) * nz.y * nf;
    fv.z = g.z + sgn(g.z) * nz.z * nf;
    fv.w = g.w + sgn(g.w) * nz.w * nf;
    uint2 o;
    o.x = (unsigned)f2bf(fv.x) | ((unsigned)f2bf(fv.y) << 16);
    o.y = (unsigned)f2bf(fv.z) | ((unsigned)f2bf(fv.w) << 16);
    int grow = (row < nAth) ? row + offA : row + offB;
    s2g[grow * 16 + c] = o;
  }
}

// Layer 2 (fused epilogue): gather bf16 s2, add noise, then
// outp = x0/3 + s1*inv1 + fv2*inv2   (fp32 output, graph-local rows)
__global__ void k_spmm2(const int* __restrict__ rowptr, const int2* __restrict__ epack,
                        const uint2* __restrict__ s2g, const uint2* __restrict__ xg,
                        const float* __restrict__ noise, float* __restrict__ outp,
                        int n, int nAth, int offA, int offB) {
  long long t = (long long)blockIdx.x * 256 + threadIdx.x;
  int row = (int)(t >> 6), lane = (int)(t & 63);
  if (row >= n) return;
  int q = lane >> 4, c = lane & 15;
  int s = rowptr[row], e = rowptr[row + 1];
  float4 a[4];
#pragma unroll
  for (int j = 0; j < 4; ++j) a[j] = (float4){0.f, 0.f, 0.f, 0.f};
  for (int kk = s; kk < e; kk += 16) {
#pragma unroll
    for (int j = 0; j < 4; ++j) {
      int i = kk + 4 * j + q;
      int2 ed = (i < e) ? epack[i] : make_int2(0, 0);
      uint2 d = s2g[ed.x * 16 + c];
      float v = __int_as_float(ed.y);
      a[j].x = fmaf(v, __uint_as_float(d.x << 16), a[j].x);
      a[j].y = fmaf(v, __uint_as_float(d.x & 0xffff0000u), a[j].y);
      a[j].z = fmaf(v, __uint_as_float(d.y << 16), a[j].z);
      a[j].w = fmaf(v, __uint_as_float(d.y & 0xffff0000u), a[j].w);
    }
  }
  float4 g;
  g.x = a[0].x + a[1].x + a[2].x + a[3].x;
  g.y = a[0].y + a[1].y + a[2].y + a[3].y;
  g.z = a[0].z + a[1].z + a[2].z + a[3].z;
  g.w = a[0].w + a[1].w + a[2].w + a[3].w;
  g.x += __shfl_xor(g.x, 16); g.y += __shfl_xor(g.y, 16);
  g.z += __shfl_xor(g.z, 16); g.w += __shfl_xor(g.w, 16);
  g.x += __shfl_xor(g.x, 32); g.y += __shfl_xor(g.y, 32);
  g.z += __shfl_xor(g.z, 32); g.w += __shfl_xor(g.w, 32);
  float4 nz = ((const float4*)(noise + (size_t)row * DD))[c];
  float nn = wave_sum(nz.x * nz.x + nz.y * nz.y + nz.z * nz.z + nz.w * nz.w) * 0.25f;
  float nf = 0.1f / fmaxf(sqrtf(nn), 1e-12f);
  float4 fv;
  fv.x = g.x + sgn(g.x) * nz.x * nf;
  fv.y = g.y + sgn(g.y) * nz.y * nf;
  fv.z = g.z + sgn(g.z) * nz.z * nf;
  fv.w = g.w + sgn(g.w) * nz.w * nf;
  float fn2 = wave_sum(fv.x * fv.x + fv.y * fv.y + fv.z * fv.z + fv.w * fv.w) * 0.25f;
  float inv2 = (1.f / 3.f) / fmaxf(sqrtf(fn2), 1e-12f);
  int grow = (row < nAth) ? row + offA : row + offB;
  // layer-1 own row (bf16) + its norm
  uint2 s1p = s2g[grow * 16 + c];
  float4 s1;
  s1.x = __uint_as_float(s1p.x << 16);
  s1.y = __uint_as_float(s1p.x & 0xffff0000u);
  s1.z = __uint_as_float(s1p.y << 16);
  s1.w = __uint_as_float(s1p.y & 0xffff0000u);
  float fn1 = wave_sum(s1.x * s1.x + s1.y * s1.y + s1.z * s1.z + s1.w * s1.w) * 0.25f;
  float inv1 = (1.f / 3.f) / fmaxf(sqrtf(fn1), 1e-12f);
  // own raw feature (bf16)
  uint2 x0p = xg[grow * 16 + c];
  float4 x0;
  x0.x = __uint_as_float(x0p.x << 16);
  x0.y = __uint_as_float(x0p.x & 0xffff0000u);
  x0.z = __uint_as_float(x0p.y << 16);
  x0.w = __uint_as_float(x0p.y & 0xffff0000u);
  if (lane < 16) {
    float4 o;
    o.x = x0.x * (1.f / 3.f) + s1.x * inv1 + fv.x * inv2;
    o.y = x0.y * (1.f / 3.f) + s1.y * inv1 + fv.y * inv2;
    o.z = x0.z * (1.f / 3.f) + s1.z * inv1 + fv.z * inv2;
    o.w = x0.w * (1.f / 3.f) + s1.w * inv1 + fv.w * inv2;
    ((float4*)(outp + (size_t)row * DD))[c] = o;
  }
}

// sampled aggregation: one wave per sample id; out[w] = agg row ids[w] (fp32 gather)
__global__ void k_agg_s(const int* __restrict__ rowptr, const int2* __restrict__ epack,
                        const float* __restrict__ x, const float* __restrict__ noise,
                        const int* __restrict__ ids, int nids, float* __restrict__ out) {
  long long t = (long long)blockIdx.x * 256 + threadIdx.x;
  int w = (int)(t >> 6), lane = (int)(t & 63);
  if (w >= nids) return;
  int row = ids[w];
  int q = lane >> 4, c = lane & 15;
  int s = rowptr[row], e = rowptr[row + 1];
  float4 a0 = {0.f, 0.f, 0.f, 0.f}, a1 = {0.f, 0.f, 0.f, 0.f};
  for (int kk = s; kk < e; kk += 8) {
    int i0 = kk + q, i1 = kk + 4 + q;
    int2 e0 = (i0 < e) ? epack[i0] : make_int2(0, 0);
    int2 e1 = (i1 < e) ? epack[i1] : make_int2(0, 0);
    float4 x0 = ((const float4*)(x + (size_t)e0.x * DD))[c];
    float4 x1 = ((const float4*)(x + (size_t)e1.x * DD))[c];
    float v0 = __int_as_float(e0.y), v1 = __int_as_float(e1.y);
    a0.x = fmaf(v0, x0.x, a0.x); a0.y = fmaf(v0, x0.y, a0.y);
    a0.z = fmaf(v0, x0.z, a0.z); a0.w = fmaf(v0, x0.w, a0.w);
    a1.x = fmaf(v1, x1.x, a1.x); a1.y = fmaf(v1, x1.y, a1.y);
    a1.z = fmaf(v1, x1.z, a1.z); a1.w = fmaf(v1, x1.w, a1.w);
  }
  float4 g;
  g.x = a0.x + a1.x; g.y = a0.y + a1.y; g.z = a0.z + a1.z; g.w = a0.w + a1.w;
  g.x += __shfl_xor(g.x, 16); g.y += __shfl_xor(g.y, 16);
  g.z += __shfl_xor(g.z, 16); g.w += __shfl_xor(g.w, 16);
  g.x += __shfl_xor(g.x, 32); g.y += __shfl_xor(g.y, 32);
  g.z += __shfl_xor(g.z, 32); g.w += __shfl_xor(g.w, 32);
  float4 nz = ((const float4*)(noise + (size_t)row * DD))[c];
  float nn = wave_sum(nz.x * nz.x + nz.y * nz.y + nz.z * nz.z + nz.w * nz.w) * 0.25f;
  float nf = 0.1f / fmaxf(sqrtf(nn), 1e-12f);
  if (lane < 16) {
    float4 fv;
    fv.x = g.x + sgn(g.x) * nz.x * nf;
    fv.y = g.y + sgn(g.y) * nz.y * nf;
    fv.z = g.z + sgn(g.z) * nz.z * nf;
    fv.w = g.w + sgn(g.w) * nz.w * nf;
    ((float4*)(out + (size_t)w * DD))[c] = fv;
  }
}

// set sampled-row flags for phase-2 filtering (biagg rows [0,20000), uiagg [20000,70000))
__global__ void k_flag(const int* __restrict__ users, const int* __restrict__ bundles,
                       unsigned char* __restrict__ flags) {
  int t = blockIdx.x * 256 + threadIdx.x;
  if (t < BATCH) flags[20000 + users[t]] = 1;
  if (t < 2 * BATCH) flags[bundles[t]] = 1;
}

// ---------------- heads ----------------

__global__ void k_bpr(const float* __restrict__ o_UI, const float* __restrict__ biuS,
                      const float* __restrict__ uibS, const float* __restrict__ o_BI,
                      const int* __restrict__ users, const int* __restrict__ bundles,
                      float* __restrict__ bpr_terms) {
  long long t = (long long)blockIdx.x * 256 + threadIdx.x;
  int w = (int)(t >> 6);
  int lane = (int)(t & 63);
  if (w >= BATCH) return;
  int u = users[w];
  int b0 = bundles[2 * w], b1 = bundles[2 * w + 1];
  float ur = 0.5f * (o_UI[(size_t)u * DD + lane] + biuS[(size_t)w * DD + lane]);
  float br0 = 0.5f * (uibS[(size_t)(2 * w) * DD + lane] + o_BI[(size_t)b0 * DD + lane]);
  float br1 = 0.5f * (uibS[(size_t)(2 * w + 1) * DD + lane] + o_BI[(size_t)b1 * DD + lane]);
  float pos = wave_sum(ur * br0);
  float neg = wave_sum(ur * br1);
  if (lane == 0) {
    float x = pos - neg;
    float loss = (x > 0.f) ? log1pf(expf(-x)) : (-x + log1pf(expf(x)));
    bpr_terms[w] = loss;
  }
}

__global__ void k_sumsq_p(const float* __restrict__ x, int n4, float* __restrict__ partials) {
  float s = 0.f;
  for (int i = blockIdx.x * 256 + threadIdx.x; i < n4; i += gridDim.x * 256) {
    float4 v = ((const float4*)x)[i];
    s += v.x * v.x + v.y * v.y + v.z * v.z + v.w * v.w;
  }
  s = wave_sum(s);
  __shared__ float part[4];
  if ((threadIdx.x & 63) == 0) part[threadIdx.x >> 6] = s;
  __syncthreads();
  if (threadIdx.x == 0) partials[blockIdx.x] = part[0] + part[1] + part[2] + part[3];
}

// build 6 normalized (2048 x 64) matrices, fp32 + bf16 copies
__global__ void k_gather(const float* __restrict__ o_UB, const float* __restrict__ o_UI,
                         const float* __restrict__ o_BI, const float* __restrict__ uibS,
                         const float* __restrict__ biuS, const int* __restrict__ users,
                         const int* __restrict__ bundles, float* __restrict__ P,
                         unsigned short* __restrict__ Pb) {
  long long t = (long long)blockIdx.x * 256 + threadIdx.x;
  int w = (int)(t >> 6);
  int lane = (int)(t & 63);
  if (w >= 6 * BATCH) return;
  int k = w / BATCH, b = w % BATCH;
  const float* src;
  if (k == 0)      src = o_UB + (size_t)users[b] * DD;
  else if (k == 1) src = o_UI + (size_t)users[b] * DD;
  else if (k == 2) src = biuS + (size_t)b * DD;
  else if (k == 3) src = o_UB + (size_t)(U_N + bundles[2 * b]) * DD;
  else if (k == 4) src = uibS + (size_t)(2 * b) * DD;
  else             src = o_BI + (size_t)bundles[2 * b] * DD;
  float v = src[lane];
  float n2 = wave_sum(v * v);
  float inv = 1.f / fmaxf(sqrtf(n2), 1e-12f);
  float pv = v * inv;
  P[(size_t)w * DD + lane] = pv;
  Pb[(size_t)w * DD + lane] = f2bf(pv);
}

// MFMA CL pair kernel: each wave computes a 64x256 S-chunk of one pair,
// ttl[p][i] += sum_j exp(4 * X_i . Y_j)   (atomic partial row-sums)
__global__ void k_clpair_mfma(const unsigned short* __restrict__ Pb,
                              float* __restrict__ ttl) {
  const int pairX[12] = {0, 0, 1, 0, 1, 2, 3, 3, 4, 3, 4, 5};
  const int pairY[12] = {1, 2, 2, 0, 1, 2, 4, 5, 5, 3, 4, 5};
  int wid = threadIdx.x >> 6;
  int lane = threadIdx.x & 63;
  int wtile = blockIdx.x * 4 + wid;     // 12 * 32 * 8 = 3072 wave-tiles
  int p = wtile >> 8;                   // / 256
  int rest = wtile & 255;
  int it = rest >> 3, jc = rest & 7;    // 64-row i-tile, 256-col j-chunk
  const unsigned short* X = Pb + (size_t)pairX[p] * BATCH * DD;
  const unsigned short* Y = Pb + (size_t)pairY[p] * BATCH * DD;
  int r = lane & 15, q = lane >> 4;
  short8 A[2][4];
#pragma unroll
  for (int kh = 0; kh < 2; ++kh)
#pragma unroll
    for (int ii = 0; ii < 4; ++ii)
      A[kh][ii] = *(const short8*)(X + (size_t)(it * 64 + ii * 16 + r) * DD + kh * 32 + q * 8);
  float rs[4][4];  // [ii][reg] row-sums of exp
#pragma unroll
  for (int ii = 0; ii < 4; ++ii)
#pragma unroll
    for (int g = 0; g < 4; ++g) rs[ii][g] = 0.f;
  for (int jn = 0; jn < 4; ++jn) {
    int j0 = jc * 256 + jn * 64;
    floatx4 acc[4][4];
#pragma unroll
    for (int ii = 0; ii < 4; ++ii)
#pragma unroll
      for (int jj = 0; jj < 4; ++jj) acc[ii][jj] = (floatx4){0.f, 0.f, 0.f, 0.f};
#pragma unroll
    for (int kh = 0; kh < 2; ++kh) {
      short8 Bf[4];
#pragma unroll
      for (int jj = 0; jj < 4; ++jj)
        Bf[jj] = *(const short8*)(Y + (size_t)(j0 + jj * 16 + r) * DD + kh * 32 + q * 8);
#pragma unroll
      for (int ii = 0; ii < 4; ++ii)
#pragma unroll
        for (int jj = 0; jj < 4; ++jj)
          acc[ii][jj] = __builtin_amdgcn_mfma_f32_16x16x32_bf16(A[kh][ii], Bf[jj],
                                                                acc[ii][jj], 0, 0, 0);
    }
#pragma unroll
    for (int ii = 0; ii < 4; ++ii)
#pragma unroll
      for (int jj = 0; jj < 4; ++jj)
#pragma unroll
        for (int g = 0; g < 4; ++g) rs[ii][g] += __expf(4.0f * acc[ii][jj][g]);
  }
#pragma unroll
  for (int off = 1; off < 16; off <<= 1)
#pragma unroll
    for (int ii = 0; ii < 4; ++ii)
#pragma unroll
      for (int g = 0; g < 4; ++g) rs[ii][g] += __shfl_xor(rs[ii][g], off);
  if (r == 0) {
#pragma unroll
    for (int ii = 0; ii < 4; ++ii)
#pragma unroll
      for (int g = 0; g < 4; ++g)
        unsafeAtomicAdd(&ttl[(size_t)p * BATCH + it * 64 + ii * 16 + q * 4 + g],
                        rs[ii][g]);
  }
}

// per (pair, i): ttl[p,i] <- log(ttl[p,i]) - diag/tau  (diag in fp32)
__global__ void k_cldiag(const float* __restrict__ P, float* __restrict__ ttl) {
  const int pairX[12] = {0, 0, 1, 0, 1, 2, 3, 3, 4, 3, 4, 5};
  const int pairY[12] = {1, 2, 2, 0, 1, 2, 4, 5, 5, 3, 4, 5};
  long long t = (long long)blockIdx.x * 256 + threadIdx.x;
  int w = (int)(t >> 6);
  int lane = (int)(t & 63);
  if (w >= 12 * BATCH) return;
  int p = w / BATCH, i = w % BATCH;
  float xv = P[((size_t)pairX[p] * BATCH + i) * DD + lane];
  float yv = P[((size_t)pairY[p] * BATCH + i) * DD + lane];
  float d = wave_sum(xv * yv);
  if (lane == 0) ttl[(size_t)p * BATCH + i] = logf(ttl[(size_t)p * BATCH + i]) - d * 4.0f;
}

__global__ void k_finalred(const float* __restrict__ bpr_terms,
                           const float* __restrict__ cl_terms,
                           const float* __restrict__ partials,
                           float* __restrict__ out) {
  int t = threadIdx.x;  // 1024
  float bpr = 0.f, reg = 0.f, inter = 0.f, intra = 0.f;
  for (int i = t; i < BATCH; i += 1024) bpr += bpr_terms[i];
  for (int i = t; i < 768; i += 1024) reg += partials[i];
  for (int i = t; i < 12 * BATCH; i += 1024) {
    int p = i >> 11;
    float v = cl_terms[i];
    if ((p % 6) < 3) inter += v; else intra += v;
  }
  bpr = wave_sum(bpr); reg = wave_sum(reg);
  inter = wave_sum(inter); intra = wave_sum(intra);
  __shared__ float sb[16], sr[16], si[16], sx[16];
  int w = t >> 6, lane = t & 63;
  if (lane == 0) { sb[w] = bpr; sr[w] = reg; si[w] = inter; sx[w] = intra; }
  __syncthreads();
  if (t == 0) {
    float Bs = 0, Rs = 0, Is = 0, Xs = 0;
    for (int i = 0; i < 16; ++i) { Bs += sb[i]; Rs += sr[i]; Is += si[i]; Xs += sx[i]; }
    out[0] = Bs / (float)BATCH + 1e-5f * Rs;
    out[1] = 0.04f * (0.5f * Is + 0.5f * Xs) / (float)BATCH;
  }
}

}  // namespace

extern "C" void kernel_launch(void* const* d_in, const int* in_sizes, int n_in,
                              void* d_out, int out_size, void* d_ws, size_t ws_size,
                              hipStream_t stream) {
  const float* usersF = (const float*)d_in[0];
  const float* bundlesF = (const float*)d_in[1];
  const float* itemsF = (const float*)d_in[2];
  const int* ub_rows = (const int*)d_in[3];
  const int* ub_cols = (const int*)d_in[4];
  const float* ub_vals = (const float*)d_in[5];
  const int* ui_rows = (const int*)d_in[6];
  const int* ui_cols = (const int*)d_in[7];
  const float* ui_vals = (const float*)d_in[8];
  const int* bi_rows = (const int*)d_in[9];
  const int* bi_cols = (const int*)d_in[10];
  const float* bi_vals = (const float*)d_in[11];
  const int* biagg_rows = (const int*)d_in[12];
  const int* biagg_cols = (const int*)d_in[13];
  const float* biagg_vals = (const float*)d_in[14];
  const int* uiagg_rows = (const int*)d_in[15];
  const int* uiagg_cols = (const int*)d_in[16];
  const float* uiagg_vals = (const float*)d_in[17];
  const float* noise_UB = (const float*)d_in[18];
  const float* noise_UI = (const float*)d_in[19];
  const float* noise_BI = (const float*)d_in[20];
  const float* noise_agg_BI = (const float*)d_in[21];
  const float* noise_agg_UI = (const float*)d_in[22];
  const int* users = (const int*)d_in[23];
  const int* bundles = (const int*)d_in[24];
  int nnz_ub = in_sizes[3], nnz_ui = in_sizes[6], nnz_bi = in_sizes[9];
  int nnz_biagg = in_sizes[12], nnz_uiagg = in_sizes[15];

  float* ws = (float*)d_ws;
  size_t off = 0;
  float* o_UB = ws + off; off += (size_t)(U_N + B_N) * DD;
  float* o_UI = ws + off; off += (size_t)(U_N + I_N) * DD;
  float* o_BI = ws + off; off += (size_t)(B_N + I_N) * DD;
  float* uibS = ws + off; off += (size_t)2 * BATCH * DD;   // rows bundles[j], j in [0,4096)
  float* biuS = ws + off; off += (size_t)BATCH * DD;       // rows users[w]
  // bf16 buffers (sized in float units: 170000*64 ushort = 5.44M floats each)
  unsigned short* s2g16 = (unsigned short*)(ws + off); off += (size_t)170000 * DD / 2;
  unsigned short* xb16  = (unsigned short*)(ws + off); off += (size_t)170000 * DD / 2;
  float* P    = ws + off; off += (size_t)6 * BATCH * DD;
  float* ttl  = ws + off; off += (size_t)12 * BATCH;
  float* bprT = ws + off; off += BATCH;
  float* prt  = ws + off; off += 768;
  int* rptr  = (int*)(ws + off); off += N1 + 1;
  int* bcnt  = (int*)(ws + off); off += 512;
  int* bbase = (int*)(ws + off); off += 520;
  int* bcur  = (int*)(ws + off); off += 512;
  unsigned char* flags = (unsigned char*)(ws + off); off += 17500;  // 70000 B
  off = (off + 1) & ~(size_t)1;  // 8B align
  int2* epack = (int2*)(ws + off); off += (size_t)5200000 * 2;
  if (ws_size < off * sizeof(float)) return;  // insufficient workspace

  // Pb (bf16 copy of P) aliases s2g16: dead after last spmm2 / phase-2 place
  unsigned short* Pb = (unsigned short*)s2g16;
  // binning staging buffers alias dead regions:
  // phase 1 (before any propagate): o_UB+o_UI region (14.08M floats >= 10.4M needed)
  int2* ebin_cv1 = (int2*)ws;
  // phase 2 (after propagates, s2g dead): s2g region (21.76 MB >= worst 14.4 MB)
  int2* ebin_cv2 = (int2*)s2g16;

  const uint2* xgv = (const uint2*)xb16;
  uint2* s2gv = (uint2*)s2g16;

  auto gb = [](int nnz) { return (nnz + 8191) / 8192; };

  // ---- bf16 conversion of input features into concat [users|bundles|items]
  k_tobf16<<<(U_N * 16 + 255) / 256, 256, 0, stream>>>(usersF, xb16, U_N * 16);
  k_tobf16<<<(B_N * 16 + 255) / 256, 256, 0, stream>>>(bundlesF, xb16 + (size_t)U_N * DD,
                                                       B_N * 16);
  k_tobf16<<<(I_N * 16 + 255) / 256, 256, 0, stream>>>(itemsF, xb16 + (size_t)(U_N + B_N) * DD,
                                                       I_N * 16);

  // ---- phase-1 CSR: UB rows [0,70000), UI rows [70000,220000), BI rows [220000,340000)
  // column/row remap constants per graph into global node space:
  //   UB: identity (nAth=INT_MAX); UI: col<50000 ? +0 : +20000; BI: always +50000 (nAth=0)
  int* rp_ub = rptr, * rp_ui = rptr + 70000, * rp_bi = rptr + 220000;
  hipMemsetAsync(bcnt, 0, 512 * sizeof(int), stream);
  k_bhist<<<gb(nnz_ub), 512, 0, stream>>>(ub_rows, nnz_ub, 0, SHIFT1, nullptr, bcnt);
  k_bhist<<<gb(nnz_ui), 512, 0, stream>>>(ui_rows, nnz_ui, 70000, SHIFT1, nullptr, bcnt);
  k_bhist<<<gb(nnz_bi), 512, 0, stream>>>(bi_rows, nnz_bi, 220000, SHIFT1, nullptr, bcnt);
  k_bucket_scan<<<1, 512, 0, stream>>>(bcnt, NB1, bbase, bcur, rptr + N1);
  k_binscatter<<<gb(nnz_ub), 512, 0, stream>>>(ub_rows, ub_cols, ub_vals, nnz_ub, 0, SHIFT1,
                                               INT_MAX, 0, 0, nullptr, bcur, ebin_cv1);
  k_binscatter<<<gb(nnz_ui), 512, 0, stream>>>(ui_rows, ui_cols, ui_vals, nnz_ui, 70000, SHIFT1,
                                               50000, 0, 20000, nullptr, bcur, ebin_cv1);
  k_binscatter<<<gb(nnz_bi), 512, 0, stream>>>(bi_rows, bi_cols, bi_vals, nnz_bi, 220000, SHIFT1,
                                               0, 50000, 50000, nullptr, bcur, ebin_cv1);
  k_place<<<NB1, 1024, 0, stream>>>(bbase, SHIFT1, N1, ebin_cv1, rptr, epack);

  auto propagate = [&](int nA, int nB, const int* rp, const float* noise, float* outp,
                       int nAth, int offA, int offB) {
    int n = nA + nB;
    int gp = (int)(((long long)n * 64 + 255) / 256);
    k_spmm1<<<gp, 256, 0, stream>>>(rp, epack, xgv, noise, s2gv, n, nAth, offA, offB);
    k_spmm2<<<gp, 256, 0, stream>>>(rp, epack, s2gv, xgv, noise + (size_t)n * DD,
                                    outp, n, nAth, offA, offB);
  };

  propagate(U_N, B_N, rp_ub, noise_UB, o_UB, INT_MAX, 0, 0);
  propagate(U_N, I_N, rp_ui, noise_UI, o_UI, 50000, 0, 20000);
  propagate(B_N, I_N, rp_bi, noise_BI, o_BI, 0, 50000, 50000);

  // ---- phase-2 CSR (sampled-row filtered): BIAGG rows [0,20000), UIAGG rows [20000,70000)
  int* rp_ba = rptr, * rp_ua = rptr + 20000;
  hipMemsetAsync(flags, 0, 70000, stream);
  k_flag<<<(2 * BATCH + 255) / 256, 256, 0, stream>>>(users, bundles, flags);
  hipMemsetAsync(bcnt, 0, 512 * sizeof(int), stream);
  k_bhist<<<gb(nnz_biagg), 512, 0, stream>>>(biagg_rows, nnz_biagg, 0, SHIFT2, flags, bcnt);
  k_bhist<<<gb(nnz_uiagg), 512, 0, stream>>>(uiagg_rows, nnz_uiagg, 20000, SHIFT2, flags, bcnt);
  k_bucket_scan<<<1, 512, 0, stream>>>(bcnt, NB2, bbase, bcur, rptr + N2);
  k_binscatter<<<gb(nnz_biagg), 512, 0, stream>>>(biagg_rows, biagg_cols, biagg_vals, nnz_biagg,
                                                  0, SHIFT2, INT_MAX, 0, 0, flags, bcur,
                                                  ebin_cv2);
  k_binscatter<<<gb(nnz_uiagg), 512, 0, stream>>>(uiagg_rows, uiagg_cols, uiagg_vals, nnz_uiagg,
                                                  20000, SHIFT2, INT_MAX, 0, 0, flags, bcur,
                                                  ebin_cv2);
  k_place<<<NB2, 1024, 0, stream>>>(bbase, SHIFT2, N2, ebin_cv2, rptr, epack);

  // sampled aggregations (only the rows the heads read); fp32 gather from o_* items
  k_agg_s<<<(2 * BATCH * 64) / 256, 256, 0, stream>>>(
      rp_ba, epack, o_UI + (size_t)U_N * DD, noise_agg_BI, bundles, 2 * BATCH, uibS);
  k_agg_s<<<(BATCH * 64) / 256, 256, 0, stream>>>(
      rp_ua, epack, o_BI + (size_t)B_N * DD, noise_agg_UI, users, BATCH, biuS);

  // heads
  k_bpr<<<BATCH * 64 / 256, 256, 0, stream>>>(o_UI, biuS, uibS, o_BI, users, bundles, bprT);
  k_sumsq_p<<<256, 256, 0, stream>>>(usersF, U_N * DD / 4, prt);
  k_sumsq_p<<<256, 256, 0, stream>>>(bundlesF, B_N * DD / 4, prt + 256);
  k_sumsq_p<<<256, 256, 0, stream>>>(itemsF, I_N * DD / 4, prt + 512);
  k_gather<<<6 * BATCH * 64 / 256, 256, 0, stream>>>(o_UB, o_UI, o_BI, uibS, biuS,
                                                     users, bundles, P, Pb);
  hipMemsetAsync(ttl, 0, (size_t)12 * BATCH * sizeof(float), stream);
  k_clpair_mfma<<<768, 256, 0, stream>>>(Pb, ttl);
  k_cldiag<<<12 * BATCH * 64 / 256, 256, 0, stream>>>(P, ttl);
  k_finalred<<<1, 1024, 0, stream>>>(bprT, ttl, prt, (float*)d_out);
}

// Round 4
// 998.138 us; speedup vs baseline: 1.7291x; 1.0673x over previous
//
#include <hip/hip_runtime.h>
#include <cmath>
#include <climits>

#define DD 64

namespace {

constexpr int U_N = 50000, B_N = 20000, I_N = 100000;
constexpr int BATCH = 2048;

// phase-1 CSR: 340000 rows, bucket = row >> 10 (1024 rows/bucket, 333 buckets)
// phase-2 CSR: 70000 rows,  bucket = row >> 8  (256 rows/bucket, 274 buckets)
constexpr int N1 = 340000, N2 = 70000;
constexpr int SHIFT1 = 10, SHIFT2 = 8;
constexpr int NB1 = (N1 + (1 << SHIFT1) - 1) >> SHIFT1;  // 333
constexpr int NB2 = (N2 + (1 << SHIFT2) - 1) >> SHIFT2;  // 274

typedef __attribute__((ext_vector_type(8))) short short8;   // 8 bf16 (4 VGPRs)
typedef __attribute__((ext_vector_type(4))) float floatx4;  // 4 fp32 acc
typedef __attribute__((ext_vector_type(2))) float f32x2;    // packed-fma pair

__device__ __forceinline__ float wave_sum(float v) {
#pragma unroll
  for (int off = 32; off > 0; off >>= 1) v += __shfl_xor(v, off);
  return v;
}

// sum across the 16 lanes of a c-group (values must be q-replicated already)
__device__ __forceinline__ float wave_sum16(float v) {
#pragma unroll
  for (int off = 1; off < 16; off <<= 1) v += __shfl_xor(v, off);
  return v;
}

__device__ __forceinline__ unsigned short f2bf(float f) {
  unsigned u = __float_as_uint(f);
  unsigned r = (u + 0x7FFFu + ((u >> 16) & 1u)) >> 16;  // RNE
  return (unsigned short)r;
}

__device__ __forceinline__ float sgn(float x) {
  return (x > 0.f) ? 1.f : ((x < 0.f) ? -1.f : 0.f);
}

// fp32 row-major -> bf16 (packed), 4 elems/thread
__global__ void k_tobf16(const float* __restrict__ x, unsigned short* __restrict__ o, int n4) {
  int i = blockIdx.x * 256 + threadIdx.x;
  if (i >= n4) return;
  float4 v = ((const float4*)x)[i];
  uint2 p;
  p.x = (unsigned)f2bf(v.x) | ((unsigned)f2bf(v.y) << 16);
  p.y = (unsigned)f2bf(v.z) | ((unsigned)f2bf(v.w) << 16);
  ((uint2*)o)[i] = p;
}

// ---------------- CSR build (two-pass bucketed binning) ----------------
__global__ __launch_bounds__(512) void k_bhist(const int* __restrict__ rows, int nnz,
                                               int row_off, int shift,
                                               const unsigned char* __restrict__ flags,
                                               int* __restrict__ bcnt) {
  __shared__ int h[512];
  int t = threadIdx.x;
  h[t] = 0;
  __syncthreads();
  int tile0 = blockIdx.x * 8192;
#pragma unroll
  for (int i = 0; i < 16; ++i) {
    int e = tile0 + i * 512 + t;
    if (e < nnz) {
      int r = rows[e] + row_off;
      if (!flags || flags[r]) atomicAdd(&h[r >> shift], 1);
    }
  }
  __syncthreads();
  if (h[t]) atomicAdd(&bcnt[t], h[t]);
}

__global__ void k_bucket_scan(const int* __restrict__ bcnt, int nb, int* __restrict__ bbase,
                              int* __restrict__ bcur, int* __restrict__ rowptr_end) {
  int t = threadIdx.x;  // 512
  int lane = t & 63, w = t >> 6;
  int v = (t < nb) ? bcnt[t] : 0;
  int inc = v;
#pragma unroll
  for (int off = 1; off < 64; off <<= 1) {
    int y = __shfl_up(inc, off);
    if (lane >= off) inc += y;
  }
  __shared__ int wsum[8];
  if (lane == 63) wsum[w] = inc;
  __syncthreads();
  int wadd = 0;
  for (int i = 0; i < w; ++i) wadd += wsum[i];
  inc += wadd;
  if (t < nb) { bbase[t] = inc - v; bcur[t] = inc - v; }
  if (t == 511) { bbase[nb] = inc; *rowptr_end = inc; }
}

// entry packs (rowlocal<<20)|globalcol; gcol = col < nAth ? col+offA : col+offB
__global__ __launch_bounds__(512) void k_binscatter(const int* __restrict__ rows,
                                                    const int* __restrict__ cols,
                                                    const float* __restrict__ vals, int nnz,
                                                    int row_off, int shift,
                                                    int nAth, int offA, int offB,
                                                    const unsigned char* __restrict__ flags,
                                                    int* __restrict__ bcur,
                                                    int2* __restrict__ ebin_cv) {
  __shared__ int cnt[512];
  __shared__ int gbase[512];
  int t = threadIdx.x;
  int tile0 = blockIdx.x * 8192;
  cnt[t] = 0;
  __syncthreads();
  int r[16], rank[16];
#pragma unroll
  for (int i = 0; i < 16; ++i) {
    int e = tile0 + i * 512 + t;
    rank[i] = -1;
    if (e < nnz) {
      r[i] = rows[e] + row_off;
      if (!flags || flags[r[i]]) rank[i] = atomicAdd(&cnt[r[i] >> shift], 1);
    }
  }
  __syncthreads();
  int c = cnt[t];
  if (c > 0) gbase[t] = atomicAdd(&bcur[t], c);
  __syncthreads();
  int mask = (1 << shift) - 1;
#pragma unroll
  for (int i = 0; i < 16; ++i) {
    int e = tile0 + i * 512 + t;
    if (rank[i] >= 0) {
      int pos = gbase[r[i] >> shift] + rank[i];
      int col = cols[e];
      int gcol = (col < nAth) ? col + offA : col + offB;
      ebin_cv[pos] = make_int2(((r[i] & mask) << 20) | gcol, __float_as_int(vals[e]));
    }
  }
}

__global__ __launch_bounds__(1024) void k_place(const int* __restrict__ bbase, int shift,
                                                int nrows, const int2* __restrict__ ebin_cv,
                                                int* __restrict__ rowptr,
                                                int2* __restrict__ epack) {
  int b = blockIdx.x;
  int bsize = 1 << shift;
  int row0 = b << shift;
  int t = threadIdx.x;
  __shared__ int rcnt[1024];
  __shared__ int wsum[16];
  int ebase = bbase[b], eend = bbase[b + 1];
  if (t < bsize) rcnt[t] = 0;
  __syncthreads();
  for (int e = ebase + t; e < eend; e += 1024)
    atomicAdd(&rcnt[ebin_cv[e].x >> 20], 1);
  __syncthreads();
  int v = (t < bsize) ? rcnt[t] : 0;
  int inc = v;
  int lane = t & 63, w = t >> 6;
#pragma unroll
  for (int off = 1; off < 64; off <<= 1) {
    int y = __shfl_up(inc, off);
    if (lane >= off) inc += y;
  }
  if (lane == 63) wsum[w] = inc;
  __syncthreads();
  int wadd = 0;
  for (int i = 0; i < w; ++i) wadd += wsum[i];
  inc += wadd;
  int excl = inc - v;  // exclusive scan of per-row counts within bucket
  int nr = nrows - row0;
  if (nr > bsize) nr = bsize;
  if (t < nr) rowptr[row0 + t] = ebase + excl;
  __syncthreads();
  if (t < bsize) rcnt[t] = excl;  // reuse as cursor
  __syncthreads();
  for (int e = ebase + t; e < eend; e += 1024) {
    int2 cv = ebin_cv[e];
    int pos = ebase + atomicAdd(&rcnt[cv.x >> 20], 1);
    epack[pos] = make_int2(cv.x & 0xFFFFF, cv.y);
  }
}

// ---------------- fused gather SPMM (bf16 feature streams) ----------------
// bf16 row = 128 B = 16 x uint2; lane c in [0,16) holds elems [4c,4c+4).
// Layer 1: gather bf16 global features, write bf16 noisy layer-1 feats (global layout).
__global__ void k_spmm1(const int* __restrict__ rowptr, const int2* __restrict__ epack,
                        const uint2* __restrict__ xg, const float* __restrict__ noise,
                        uint2* __restrict__ s2g, int n, int nAth, int offA, int offB) {
  long long t = (long long)blockIdx.x * 256 + threadIdx.x;
  int row = (int)(t >> 6), lane = (int)(t & 63);
  if (row >= n) return;
  int q = lane >> 4, c = lane & 15;
  unsigned cb = (unsigned)c << 3;
  int s = rowptr[row], e = rowptr[row + 1];
  int em1 = e - 1;
  f32x2 a0[4], a1[4];
#pragma unroll
  for (int j = 0; j < 4; ++j) { a0[j] = (f32x2){0.f, 0.f}; a1[j] = (f32x2){0.f, 0.f}; }
  for (int kk = s; kk < e; kk += 16) {
#pragma unroll
    for (int j = 0; j < 4; ++j) {
      int i = kk + 4 * j + q;
      int ic = min(i, em1);
      int2 ed = epack[ic];
      float v = (i <= em1) ? __int_as_float(ed.y) : 0.f;
      uint2 d = *(const uint2*)((const char*)xg + (((unsigned)ed.x << 7) | cb));
      f32x2 lo = {__uint_as_float(d.x << 16), __uint_as_float(d.x & 0xffff0000u)};
      f32x2 hi = {__uint_as_float(d.y << 16), __uint_as_float(d.y & 0xffff0000u)};
      f32x2 vv = {v, v};
      a0[j] = __builtin_elementwise_fma(lo, vv, a0[j]);
      a1[j] = __builtin_elementwise_fma(hi, vv, a1[j]);
    }
  }
  f32x2 g0 = (a0[0] + a0[1]) + (a0[2] + a0[3]);
  f32x2 g1 = (a1[0] + a1[1]) + (a1[2] + a1[3]);
  float4 g = {g0.x, g0.y, g1.x, g1.y};
  g.x += __shfl_xor(g.x, 16); g.y += __shfl_xor(g.y, 16);
  g.z += __shfl_xor(g.z, 16); g.w += __shfl_xor(g.w, 16);
  g.x += __shfl_xor(g.x, 32); g.y += __shfl_xor(g.y, 32);
  g.z += __shfl_xor(g.z, 32); g.w += __shfl_xor(g.w, 32);
  float4 nz = ((const float4*)(noise + (size_t)row * DD))[c];
  float nn = wave_sum16(nz.x * nz.x + nz.y * nz.y + nz.z * nz.z + nz.w * nz.w) * 0.25f;
  float nf = 0.1f / fmaxf(sqrtf(nn), 1e-12f);
  if (lane < 16) {
    float4 fv;
    fv.x = g.x + sgn(g.x) * nz.x * nf;
    fv.y = g.y + sgn(g.y) * nz.y * nf;
    fv.z = g.z + sgn(g.z) * nz.z * nf;
    fv.w = g.w + sgn(g.w) * nz.w * nf;
    uint2 o;
    o.x = (unsigned)f2bf(fv.x) | ((unsigned)f2bf(fv.y) << 16);
    o.y = (unsigned)f2bf(fv.z) | ((unsigned)f2bf(fv.w) << 16);
    int grow = (row < nAth) ? row + offA : row + offB;
    s2g[grow * 16 + c] = o;
  }
}

// Layer 2, sampled: local row = ids ? ids[w]+row_add : row0+w; output row w of outp.
// outp = x0/3 + s1*inv1 + fv2*inv2
__global__ void k_spmm2(const int* __restrict__ rowptr, const int2* __restrict__ epack,
                        const uint2* __restrict__ s2g, const uint2* __restrict__ xg,
                        const float* __restrict__ noise, float* __restrict__ outp,
                        const int* __restrict__ ids, int row_add, int row0, int nw,
                        int nAth, int offA, int offB) {
  long long t = (long long)blockIdx.x * 256 + threadIdx.x;
  int w = (int)(t >> 6), lane = (int)(t & 63);
  if (w >= nw) return;
  int row = ids ? (ids[w] + row_add) : (row0 + w);
  int q = lane >> 4, c = lane & 15;
  unsigned cb = (unsigned)c << 3;
  int s = rowptr[row], e = rowptr[row + 1];
  int em1 = e - 1;
  f32x2 a0[4], a1[4];
#pragma unroll
  for (int j = 0; j < 4; ++j) { a0[j] = (f32x2){0.f, 0.f}; a1[j] = (f32x2){0.f, 0.f}; }
  for (int kk = s; kk < e; kk += 16) {
#pragma unroll
    for (int j = 0; j < 4; ++j) {
      int i = kk + 4 * j + q;
      int ic = min(i, em1);
      int2 ed = epack[ic];
      float v = (i <= em1) ? __int_as_float(ed.y) : 0.f;
      uint2 d = *(const uint2*)((const char*)s2g + (((unsigned)ed.x << 7) | cb));
      f32x2 lo = {__uint_as_float(d.x << 16), __uint_as_float(d.x & 0xffff0000u)};
      f32x2 hi = {__uint_as_float(d.y << 16), __uint_as_float(d.y & 0xffff0000u)};
      f32x2 vv = {v, v};
      a0[j] = __builtin_elementwise_fma(lo, vv, a0[j]);
      a1[j] = __builtin_elementwise_fma(hi, vv, a1[j]);
    }
  }
  f32x2 g0 = (a0[0] + a0[1]) + (a0[2] + a0[3]);
  f32x2 g1 = (a1[0] + a1[1]) + (a1[2] + a1[3]);
  float4 g = {g0.x, g0.y, g1.x, g1.y};
  g.x += __shfl_xor(g.x, 16); g.y += __shfl_xor(g.y, 16);
  g.z += __shfl_xor(g.z, 16); g.w += __shfl_xor(g.w, 16);
  g.x += __shfl_xor(g.x, 32); g.y += __shfl_xor(g.y, 32);
  g.z += __shfl_xor(g.z, 32); g.w += __shfl_xor(g.w, 32);
  float4 nz = ((const float4*)(noise + (size_t)row * DD))[c];
  float nn = wave_sum16(nz.x * nz.x + nz.y * nz.y + nz.z * nz.z + nz.w * nz.w) * 0.25f;
  float nf = 0.1f / fmaxf(sqrtf(nn), 1e-12f);
  float4 fv;
  fv.x = g.x + sgn(g.x) * nz.x * nf;
  fv.y = g.y + sgn(g.y) * nz.y * nf;
  fv.z = g.z + sgn(g.z) * nz.z * nf;
  fv.w = g.w + sgn(g.w) * nz.w * nf;
  float fn2 = wave_sum16(fv.x * fv.x + fv.y * fv.y + fv.z * fv.z + fv.w * fv.w) * 0.25f;
  float inv2 = (1.f / 3.f) / fmaxf(sqrtf(fn2), 1e-12f);
  int grow = (row < nAth) ? row + offA : row + offB;
  uint2 s1p = s2g[grow * 16 + c];
  float4 s1;
  s1.x = __uint_as_float(s1p.x << 16);
  s1.y = __uint_as_float(s1p.x & 0xffff0000u);
  s1.z = __uint_as_float(s1p.y << 16);
  s1.w = __uint_as_float(s1p.y & 0xffff0000u);
  float fn1 = wave_sum16(s1.x * s1.x + s1.y * s1.y + s1.z * s1.z + s1.w * s1.w) * 0.25f;
  float inv1 = (1.f / 3.f) / fmaxf(sqrtf(fn1), 1e-12f);
  uint2 x0p = xg[grow * 16 + c];
  float4 x0;
  x0.x = __uint_as_float(x0p.x << 16);
  x0.y = __uint_as_float(x0p.x & 0xffff0000u);
  x0.z = __uint_as_float(x0p.y << 16);
  x0.w = __uint_as_float(x0p.y & 0xffff0000u);
  if (lane < 16) {
    float4 o;
    o.x = x0.x * (1.f / 3.f) + s1.x * inv1 + fv.x * inv2;
    o.y = x0.y * (1.f / 3.f) + s1.y * inv1 + fv.y * inv2;
    o.z = x0.z * (1.f / 3.f) + s1.z * inv1 + fv.z * inv2;
    o.w = x0.w * (1.f / 3.f) + s1.w * inv1 + fv.w * inv2;
    ((float4*)(outp + (size_t)w * DD))[c] = o;
  }
}

// sampled aggregation: one wave per sample id; out[w] = agg row ids[w] (fp32 gather)
__global__ void k_agg_s(const int* __restrict__ rowptr, const int2* __restrict__ epack,
                        const float* __restrict__ x, const float* __restrict__ noise,
                        const int* __restrict__ ids, int nids, float* __restrict__ out) {
  long long t = (long long)blockIdx.x * 256 + threadIdx.x;
  int w = (int)(t >> 6), lane = (int)(t & 63);
  if (w >= nids) return;
  int row = ids[w];
  int q = lane >> 4, c = lane & 15;
  int s = rowptr[row], e = rowptr[row + 1];
  int em1 = e - 1;
  float4 a0 = {0.f, 0.f, 0.f, 0.f}, a1 = {0.f, 0.f, 0.f, 0.f};
  for (int kk = s; kk < e; kk += 8) {
    int i0 = kk + q, i1 = kk + 4 + q;
    int2 e0 = epack[min(i0, em1)];
    int2 e1 = epack[min(i1, em1)];
    float4 x0 = ((const float4*)(x + (size_t)e0.x * DD))[c];
    float4 x1 = ((const float4*)(x + (size_t)e1.x * DD))[c];
    float v0 = (i0 <= em1) ? __int_as_float(e0.y) : 0.f;
    float v1 = (i1 <= em1) ? __int_as_float(e1.y) : 0.f;
    a0.x = fmaf(v0, x0.x, a0.x); a0.y = fmaf(v0, x0.y, a0.y);
    a0.z = fmaf(v0, x0.z, a0.z); a0.w = fmaf(v0, x0.w, a0.w);
    a1.x = fmaf(v1, x1.x, a1.x); a1.y = fmaf(v1, x1.y, a1.y);
    a1.z = fmaf(v1, x1.z, a1.z); a1.w = fmaf(v1, x1.w, a1.w);
  }
  float4 g;
  g.x = a0.x + a1.x; g.y = a0.y + a1.y; g.z = a0.z + a1.z; g.w = a0.w + a1.w;
  g.x += __shfl_xor(g.x, 16); g.y += __shfl_xor(g.y, 16);
  g.z += __shfl_xor(g.z, 16); g.w += __shfl_xor(g.w, 16);
  g.x += __shfl_xor(g.x, 32); g.y += __shfl_xor(g.y, 32);
  g.z += __shfl_xor(g.z, 32); g.w += __shfl_xor(g.w, 32);
  float4 nz = ((const float4*)(noise + (size_t)row * DD))[c];
  float nn = wave_sum16(nz.x * nz.x + nz.y * nz.y + nz.z * nz.z + nz.w * nz.w) * 0.25f;
  float nf = 0.1f / fmaxf(sqrtf(nn), 1e-12f);
  if (lane < 16) {
    float4 fv;
    fv.x = g.x + sgn(g.x) * nz.x * nf;
    fv.y = g.y + sgn(g.y) * nz.y * nf;
    fv.z = g.z + sgn(g.z) * nz.z * nf;
    fv.w = g.w + sgn(g.w) * nz.w * nf;
    ((float4*)(out + (size_t)w * DD))[c] = fv;
  }
}

// set sampled-row flags for phase-2 filtering (biagg rows [0,20000), uiagg [20000,70000))
__global__ void k_flag(const int* __restrict__ users, const int* __restrict__ bundles,
                       unsigned char* __restrict__ flags) {
  int t = blockIdx.x * 256 + threadIdx.x;
  if (t < BATCH) flags[20000 + users[t]] = 1;
  if (t < 2 * BATCH) flags[bundles[t]] = 1;
}

// ---------------- heads ----------------
// All rep inputs are compact now (indexed by batch slot, not node id).
__global__ void k_bpr(const float* __restrict__ o_UIuS, const float* __restrict__ biuS,
                      const float* __restrict__ uibS, const float* __restrict__ o_BIbS,
                      float* __restrict__ bpr_terms) {
  long long t = (long long)blockIdx.x * 256 + threadIdx.x;
  int w = (int)(t >> 6);
  int lane = (int)(t & 63);
  if (w >= BATCH) return;
  float ur = 0.5f * (o_UIuS[(size_t)w * DD + lane] + biuS[(size_t)w * DD + lane]);
  float br0 = 0.5f * (uibS[(size_t)(2 * w) * DD + lane] + o_BIbS[(size_t)(2 * w) * DD + lane]);
  float br1 = 0.5f * (uibS[(size_t)(2 * w + 1) * DD + lane] +
                      o_BIbS[(size_t)(2 * w + 1) * DD + lane]);
  float pos = wave_sum(ur * br0);
  float neg = wave_sum(ur * br1);
  if (lane == 0) {
    float x = pos - neg;
    float loss = (x > 0.f) ? log1pf(expf(-x)) : (-x + log1pf(expf(x)));
    bpr_terms[w] = loss;
  }
}

__global__ void k_sumsq_p(const float* __restrict__ x, int n4, float* __restrict__ partials) {
  float s = 0.f;
  for (int i = blockIdx.x * 256 + threadIdx.x; i < n4; i += gridDim.x * 256) {
    float4 v = ((const float4*)x)[i];
    s += v.x * v.x + v.y * v.y + v.z * v.z + v.w * v.w;
  }
  s = wave_sum(s);
  __shared__ float part[4];
  if ((threadIdx.x & 63) == 0) part[threadIdx.x >> 6] = s;
  __syncthreads();
  if (threadIdx.x == 0) partials[blockIdx.x] = part[0] + part[1] + part[2] + part[3];
}

// build 6 normalized (2048 x 64) matrices, fp32 + bf16 copies (all-compact sources)
__global__ void k_gather(const float* __restrict__ o_UBS, const float* __restrict__ o_UIuS,
                         const float* __restrict__ o_BIbS, const float* __restrict__ uibS,
                         const float* __restrict__ biuS, float* __restrict__ P,
                         unsigned short* __restrict__ Pb) {
  long long t = (long long)blockIdx.x * 256 + threadIdx.x;
  int w = (int)(t >> 6);
  int lane = (int)(t & 63);
  if (w >= 6 * BATCH) return;
  int k = w / BATCH, b = w % BATCH;
  const float* src;
  if (k == 0)      src = o_UBS + (size_t)b * DD;
  else if (k == 1) src = o_UIuS + (size_t)b * DD;
  else if (k == 2) src = biuS + (size_t)b * DD;
  else if (k == 3) src = o_UBS + (size_t)(2048 + 2 * b) * DD;
  else if (k == 4) src = uibS + (size_t)(2 * b) * DD;
  else             src = o_BIbS + (size_t)(2 * b) * DD;
  float v = src[lane];
  float n2 = wave_sum(v * v);
  float inv = 1.f / fmaxf(sqrtf(n2), 1e-12f);
  float pv = v * inv;
  P[(size_t)w * DD + lane] = pv;
  Pb[(size_t)w * DD + lane] = f2bf(pv);
}

// MFMA CL pair kernel: ttl[p][i] += sum_j exp(4 * X_i . Y_j)
__global__ void k_clpair_mfma(const unsigned short* __restrict__ Pb,
                              float* __restrict__ ttl) {
  const int pairX[12] = {0, 0, 1, 0, 1, 2, 3, 3, 4, 3, 4, 5};
  const int pairY[12] = {1, 2, 2, 0, 1, 2, 4, 5, 5, 3, 4, 5};
  int wid = threadIdx.x >> 6;
  int lane = threadIdx.x & 63;
  int wtile = blockIdx.x * 4 + wid;     // 12 * 32 * 8 = 3072 wave-tiles
  int p = wtile >> 8;
  int rest = wtile & 255;
  int it = rest >> 3, jc = rest & 7;    // 64-row i-tile, 256-col j-chunk
  const unsigned short* X = Pb + (size_t)pairX[p] * BATCH * DD;
  const unsigned short* Y = Pb + (size_t)pairY[p] * BATCH * DD;
  int r = lane & 15, q = lane >> 4;
  short8 A[2][4];
#pragma unroll
  for (int kh = 0; kh < 2; ++kh)
#pragma unroll
    for (int ii = 0; ii < 4; ++ii)
      A[kh][ii] = *(const short8*)(X + (size_t)(it * 64 + ii * 16 + r) * DD + kh * 32 + q * 8);
  float rs[4][4];
#pragma unroll
  for (int ii = 0; ii < 4; ++ii)
#pragma unroll
    for (int g = 0; g < 4; ++g) rs[ii][g] = 0.f;
  for (int jn = 0; jn < 4; ++jn) {
    int j0 = jc * 256 + jn * 64;
    floatx4 acc[4][4];
#pragma unroll
    for (int ii = 0; ii < 4; ++ii)
#pragma unroll
      for (int jj = 0; jj < 4; ++jj) acc[ii][jj] = (floatx4){0.f, 0.f, 0.f, 0.f};
#pragma unroll
    for (int kh = 0; kh < 2; ++kh) {
      short8 Bf[4];
#pragma unroll
      for (int jj = 0; jj < 4; ++jj)
        Bf[jj] = *(const short8*)(Y + (size_t)(j0 + jj * 16 + r) * DD + kh * 32 + q * 8);
#pragma unroll
      for (int ii = 0; ii < 4; ++ii)
#pragma unroll
        for (int jj = 0; jj < 4; ++jj)
          acc[ii][jj] = __builtin_amdgcn_mfma_f32_16x16x32_bf16(A[kh][ii], Bf[jj],
                                                                acc[ii][jj], 0, 0, 0);
    }
#pragma unroll
    for (int ii = 0; ii < 4; ++ii)
#pragma unroll
      for (int jj = 0; jj < 4; ++jj)
#pragma unroll
        for (int g = 0; g < 4; ++g) rs[ii][g] += __expf(4.0f * acc[ii][jj][g]);
  }
#pragma unroll
  for (int off = 1; off < 16; off <<= 1)
#pragma unroll
    for (int ii = 0; ii < 4; ++ii)
#pragma unroll
      for (int g = 0; g < 4; ++g) rs[ii][g] += __shfl_xor(rs[ii][g], off);
  if (r == 0) {
#pragma unroll
    for (int ii = 0; ii < 4; ++ii)
#pragma unroll
      for (int g = 0; g < 4; ++g)
        unsafeAtomicAdd(&ttl[(size_t)p * BATCH + it * 64 + ii * 16 + q * 4 + g],
                        rs[ii][g]);
  }
}

// per (pair, i): ttl[p,i] <- log(ttl[p,i]) - diag/tau
__global__ void k_cldiag(const float* __restrict__ P, float* __restrict__ ttl) {
  const int pairX[12] = {0, 0, 1, 0, 1, 2, 3, 3, 4, 3, 4, 5};
  const int pairY[12] = {1, 2, 2, 0, 1, 2, 4, 5, 5, 3, 4, 5};
  long long t = (long long)blockIdx.x * 256 + threadIdx.x;
  int w = (int)(t >> 6);
  int lane = (int)(t & 63);
  if (w >= 12 * BATCH) return;
  int p = w / BATCH, i = w % BATCH;
  float xv = P[((size_t)pairX[p] * BATCH + i) * DD + lane];
  float yv = P[((size_t)pairY[p] * BATCH + i) * DD + lane];
  float d = wave_sum(xv * yv);
  if (lane == 0) ttl[(size_t)p * BATCH + i] = logf(ttl[(size_t)p * BATCH + i]) - d * 4.0f;
}

__global__ void k_finalred(const float* __restrict__ bpr_terms,
                           const float* __restrict__ cl_terms,
                           const float* __restrict__ partials,
                           float* __restrict__ out) {
  int t = threadIdx.x;  // 1024
  float bpr = 0.f, reg = 0.f, inter = 0.f, intra = 0.f;
  for (int i = t; i < BATCH; i += 1024) bpr += bpr_terms[i];
  for (int i = t; i < 768; i += 1024) reg += partials[i];
  for (int i = t; i < 12 * BATCH; i += 1024) {
    int p = i >> 11;
    float v = cl_terms[i];
    if ((p % 6) < 3) inter += v; else intra += v;
  }
  bpr = wave_sum(bpr); reg = wave_sum(reg);
  inter = wave_sum(inter); intra = wave_sum(intra);
  __shared__ float sb[16], sr[16], si[16], sx[16];
  int w = t >> 6, lane = t & 63;
  if (lane == 0) { sb[w] = bpr; sr[w] = reg; si[w] = inter; sx[w] = intra; }
  __syncthreads();
  if (t == 0) {
    float Bs = 0, Rs = 0, Is = 0, Xs = 0;
    for (int i = 0; i < 16; ++i) { Bs += sb[i]; Rs += sr[i]; Is += si[i]; Xs += sx[i]; }
    out[0] = Bs / (float)BATCH + 1e-5f * Rs;
    out[1] = 0.04f * (0.5f * Is + 0.5f * Xs) / (float)BATCH;
  }
}

}  // namespace

extern "C" void kernel_launch(void* const* d_in, const int* in_sizes, int n_in,
                              void* d_out, int out_size, void* d_ws, size_t ws_size,
                              hipStream_t stream) {
  const float* usersF = (const float*)d_in[0];
  const float* bundlesF = (const float*)d_in[1];
  const float* itemsF = (const float*)d_in[2];
  const int* ub_rows = (const int*)d_in[3];
  const int* ub_cols = (const int*)d_in[4];
  const float* ub_vals = (const float*)d_in[5];
  const int* ui_rows = (const int*)d_in[6];
  const int* ui_cols = (const int*)d_in[7];
  const float* ui_vals = (const float*)d_in[8];
  const int* bi_rows = (const int*)d_in[9];
  const int* bi_cols = (const int*)d_in[10];
  const float* bi_vals = (const float*)d_in[11];
  const int* biagg_rows = (const int*)d_in[12];
  const int* biagg_cols = (const int*)d_in[13];
  const float* biagg_vals = (const float*)d_in[14];
  const int* uiagg_rows = (const int*)d_in[15];
  const int* uiagg_cols = (const int*)d_in[16];
  const float* uiagg_vals = (const float*)d_in[17];
  const float* noise_UB = (const float*)d_in[18];
  const float* noise_UI = (const float*)d_in[19];
  const float* noise_BI = (const float*)d_in[20];
  const float* noise_agg_BI = (const float*)d_in[21];
  const float* noise_agg_UI = (const float*)d_in[22];
  const int* users = (const int*)d_in[23];
  const int* bundles = (const int*)d_in[24];
  int nnz_ub = in_sizes[3], nnz_ui = in_sizes[6], nnz_bi = in_sizes[9];
  int nnz_biagg = in_sizes[12], nnz_uiagg = in_sizes[15];

  float* ws = (float*)d_ws;
  size_t off = 0;
  // compact spmm2 outputs
  float* o_UBS  = ws + off; off += (size_t)(3 * BATCH) * DD;   // [0,2048)=users, [2048,6144)=bundles
  float* o_UIuS = ws + off; off += (size_t)BATCH * DD;
  float* o_UIit = ws + off; off += (size_t)I_N * DD;           // UI item rows (full)
  float* o_BIbS = ws + off; off += (size_t)(2 * BATCH) * DD;
  float* o_BIit = ws + off; off += (size_t)I_N * DD;           // BI item rows (full)
  float* uibS = ws + off; off += (size_t)2 * BATCH * DD;
  float* biuS = ws + off; off += (size_t)BATCH * DD;
  // bf16 buffers (sized in float units: 170000*64 ushort = 5.44M floats each)
  unsigned short* s2g16 = (unsigned short*)(ws + off); off += (size_t)170000 * DD / 2;
  unsigned short* xb16  = (unsigned short*)(ws + off); off += (size_t)170000 * DD / 2;
  float* P    = ws + off; off += (size_t)6 * BATCH * DD;
  float* ttl  = ws + off; off += (size_t)12 * BATCH;
  float* bprT = ws + off; off += BATCH;
  float* prt  = ws + off; off += 768;
  int* rptr  = (int*)(ws + off); off += N1 + 1;
  int* bcnt  = (int*)(ws + off); off += 512;
  int* bbase = (int*)(ws + off); off += 520;
  int* bcur  = (int*)(ws + off); off += 512;
  unsigned char* flags = (unsigned char*)(ws + off); off += 17500;  // 70000 B
  off = (off + 1) & ~(size_t)1;  // 8B align
  int2* epack = (int2*)(ws + off); off += (size_t)5200000 * 2;
  if (ws_size < off * sizeof(float)) return;  // insufficient workspace

  // Pb (bf16 copy of P) aliases s2g16: dead after phase-2 k_place
  unsigned short* Pb = (unsigned short*)s2g16;
  // binning staging aliases:
  // phase 1: head compact/full output region (13.98M floats >= 10.4M needed),
  //          consumed by k_place before any spmm2/agg writes to it.
  int2* ebin_cv1 = (int2*)ws;
  // phase 2: s2g region (5.44M floats = 2.72M int2 >= filtered nnz), s2g dead after spmm2s.
  int2* ebin_cv2 = (int2*)s2g16;

  const uint2* xgv = (const uint2*)xb16;
  uint2* s2gv = (uint2*)s2g16;

  auto gb = [](int nnz) { return (nnz + 8191) / 8192; };

  // ---- bf16 conversion of input features into concat [users|bundles|items]
  k_tobf16<<<(U_N * 16 + 255) / 256, 256, 0, stream>>>(usersF, xb16, U_N * 16);
  k_tobf16<<<(B_N * 16 + 255) / 256, 256, 0, stream>>>(bundlesF, xb16 + (size_t)U_N * DD,
                                                       B_N * 16);
  k_tobf16<<<(I_N * 16 + 255) / 256, 256, 0, stream>>>(itemsF, xb16 + (size_t)(U_N + B_N) * DD,
                                                       I_N * 16);

  // ---- phase-1 CSR: UB rows [0,70000), UI rows [70000,220000), BI rows [220000,340000)
  int* rp_ub = rptr, * rp_ui = rptr + 70000, * rp_bi = rptr + 220000;
  hipMemsetAsync(bcnt, 0, 512 * sizeof(int), stream);
  k_bhist<<<gb(nnz_ub), 512, 0, stream>>>(ub_rows, nnz_ub, 0, SHIFT1, nullptr, bcnt);
  k_bhist<<<gb(nnz_ui), 512, 0, stream>>>(ui_rows, nnz_ui, 70000, SHIFT1, nullptr, bcnt);
  k_bhist<<<gb(nnz_bi), 512, 0, stream>>>(bi_rows, nnz_bi, 220000, SHIFT1, nullptr, bcnt);
  k_bucket_scan<<<1, 512, 0, stream>>>(bcnt, NB1, bbase, bcur, rptr + N1);
  k_binscatter<<<gb(nnz_ub), 512, 0, stream>>>(ub_rows, ub_cols, ub_vals, nnz_ub, 0, SHIFT1,
                                               INT_MAX, 0, 0, nullptr, bcur, ebin_cv1);
  k_binscatter<<<gb(nnz_ui), 512, 0, stream>>>(ui_rows, ui_cols, ui_vals, nnz_ui, 70000, SHIFT1,
                                               50000, 0, 20000, nullptr, bcur, ebin_cv1);
  k_binscatter<<<gb(nnz_bi), 512, 0, stream>>>(bi_rows, bi_cols, bi_vals, nnz_bi, 220000, SHIFT1,
                                               0, 50000, 50000, nullptr, bcur, ebin_cv1);
  k_place<<<NB1, 1024, 0, stream>>>(bbase, SHIFT1, N1, ebin_cv1, rptr, epack);

  // ---- propagates: spmm1 full, spmm2 only for consumed rows
  // UB: layer1 full (70K rows), layer2 sampled users+bundles only
  {
    int n = 70000;
    k_spmm1<<<(int)(((long long)n * 64 + 255) / 256), 256, 0, stream>>>(
        rp_ub, epack, xgv, noise_UB, s2gv, n, INT_MAX, 0, 0);
    const float* nz2 = noise_UB + (size_t)n * DD;
    k_spmm2<<<BATCH * 64 / 256, 256, 0, stream>>>(rp_ub, epack, s2gv, xgv, nz2, o_UBS,
                                                  users, 0, 0, BATCH, INT_MAX, 0, 0);
    k_spmm2<<<2 * BATCH * 64 / 256, 256, 0, stream>>>(rp_ub, epack, s2gv, xgv, nz2,
                                                      o_UBS + (size_t)2048 * DD,
                                                      bundles, 50000, 0, 2 * BATCH,
                                                      INT_MAX, 0, 0);
  }
  // UI: layer1 full (150K), layer2 = sampled users + all items
  {
    int n = 150000;
    k_spmm1<<<(int)(((long long)n * 64 + 255) / 256), 256, 0, stream>>>(
        rp_ui, epack, xgv, noise_UI, s2gv, n, 50000, 0, 20000);
    const float* nz2 = noise_UI + (size_t)n * DD;
    k_spmm2<<<BATCH * 64 / 256, 256, 0, stream>>>(rp_ui, epack, s2gv, xgv, nz2, o_UIuS,
                                                  users, 0, 0, BATCH, 50000, 0, 20000);
    k_spmm2<<<(int)(((long long)I_N * 64 + 255) / 256), 256, 0, stream>>>(
        rp_ui, epack, s2gv, xgv, nz2, o_UIit, nullptr, 0, 50000, I_N, 50000, 0, 20000);
  }
  // BI: layer1 full (120K), layer2 = sampled bundles + all items
  {
    int n = 120000;
    k_spmm1<<<(int)(((long long)n * 64 + 255) / 256), 256, 0, stream>>>(
        rp_bi, epack, xgv, noise_BI, s2gv, n, 0, 50000, 50000);
    const float* nz2 = noise_BI + (size_t)n * DD;
    k_spmm2<<<2 * BATCH * 64 / 256, 256, 0, stream>>>(rp_bi, epack, s2gv, xgv, nz2, o_BIbS,
                                                      bundles, 0, 0, 2 * BATCH, 0, 50000,
                                                      50000);
    k_spmm2<<<(int)(((long long)I_N * 64 + 255) / 256), 256, 0, stream>>>(
        rp_bi, epack, s2gv, xgv, nz2, o_BIit, nullptr, 0, 20000, I_N, 0, 50000, 50000);
  }

  // ---- phase-2 CSR (sampled-row filtered): BIAGG rows [0,20000), UIAGG rows [20000,70000)
  int* rp_ba = rptr, * rp_ua = rptr + 20000;
  hipMemsetAsync(flags, 0, 70000, stream);
  k_flag<<<(2 * BATCH + 255) / 256, 256, 0, stream>>>(users, bundles, flags);
  hipMemsetAsync(bcnt, 0, 512 * sizeof(int), stream);
  k_bhist<<<gb(nnz_biagg), 512, 0, stream>>>(biagg_rows, nnz_biagg, 0, SHIFT2, flags, bcnt);
  k_bhist<<<gb(nnz_uiagg), 512, 0, stream>>>(uiagg_rows, nnz_uiagg, 20000, SHIFT2, flags, bcnt);
  k_bucket_scan<<<1, 512, 0, stream>>>(bcnt, NB2, bbase, bcur, rptr + N2);
  k_binscatter<<<gb(nnz_biagg), 512, 0, stream>>>(biagg_rows, biagg_cols, biagg_vals, nnz_biagg,
                                                  0, SHIFT2, INT_MAX, 0, 0, flags, bcur,
                                                  ebin_cv2);
  k_binscatter<<<gb(nnz_uiagg), 512, 0, stream>>>(uiagg_rows, uiagg_cols, uiagg_vals, nnz_uiagg,
                                                  20000, SHIFT2, INT_MAX, 0, 0, flags, bcur,
                                                  ebin_cv2);
  k_place<<<NB2, 1024, 0, stream>>>(bbase, SHIFT2, N2, ebin_cv2, rptr, epack);

  // sampled aggregations gather the full item-row outputs
  k_agg_s<<<(2 * BATCH * 64) / 256, 256, 0, stream>>>(
      rp_ba, epack, o_UIit, noise_agg_BI, bundles, 2 * BATCH, uibS);
  k_agg_s<<<(BATCH * 64) / 256, 256, 0, stream>>>(
      rp_ua, epack, o_BIit, noise_agg_UI, users, BATCH, biuS);

  // heads
  k_bpr<<<BATCH * 64 / 256, 256, 0, stream>>>(o_UIuS, biuS, uibS, o_BIbS, bprT);
  k_sumsq_p<<<256, 256, 0, stream>>>(usersF, U_N * DD / 4, prt);
  k_sumsq_p<<<256, 256, 0, stream>>>(bundlesF, B_N * DD / 4, prt + 256);
  k_sumsq_p<<<256, 256, 0, stream>>>(itemsF, I_N * DD / 4, prt + 512);
  k_gather<<<6 * BATCH * 64 / 256, 256, 0, stream>>>(o_UBS, o_UIuS, o_BIbS, uibS, biuS,
                                                     P, Pb);
  hipMemsetAsync(ttl, 0, (size_t)12 * BATCH * sizeof(float), stream);
  k_clpair_mfma<<<768, 256, 0, stream>>>(Pb, ttl);
  k_cldiag<<<12 * BATCH * 64 / 256, 256, 0, stream>>>(P, ttl);
  k_finalred<<<1, 1024, 0, stream>>>(bprT, ttl, prt, (float*)d_out);
}

// Round 5
// 862.932 us; speedup vs baseline: 2.0000x; 1.1567x over previous
//
#include <hip/hip_runtime.h>
#include <cmath>
#include <climits>

#define DD 64

namespace {

constexpr int U_N = 50000, B_N = 20000, I_N = 100000;
constexpr int BATCH = 2048;

constexpr int N1 = 340000, N2 = 70000;
constexpr int SHIFT1 = 10, SHIFT2 = 8;
constexpr int NB1 = (N1 + (1 << SHIFT1) - 1) >> SHIFT1;  // 333
constexpr int NB2 = (N2 + (1 << SHIFT2) - 1) >> SHIFT2;  // 274

typedef __attribute__((ext_vector_type(8))) short short8;   // 8 bf16 (4 VGPRs)
typedef __attribute__((ext_vector_type(4))) float floatx4;  // 4 fp32 acc
typedef __attribute__((ext_vector_type(2))) float f32x2;    // packed-fma pair
typedef __attribute__((ext_vector_type(4))) float f4v;      // nt-load vector
typedef __attribute__((ext_vector_type(2))) int i2v;        // nt-load epack

__device__ __forceinline__ float wave_sum(float v) {
#pragma unroll
  for (int off = 32; off > 0; off >>= 1) v += __shfl_xor(v, off);
  return v;
}

// sum across 16 lanes of a c-group (lane bits 0..3)
__device__ __forceinline__ float wave_sum16(float v) {
#pragma unroll
  for (int off = 1; off < 16; off <<= 1) v += __shfl_xor(v, off);
  return v;
}

__device__ __forceinline__ unsigned short f2bf(float f) {
  unsigned u = __float_as_uint(f);
  unsigned r = (u + 0x7FFFu + ((u >> 16) & 1u)) >> 16;  // RNE
  return (unsigned short)r;
}

__device__ __forceinline__ float sgn(float x) {
  return (x > 0.f) ? 1.f : ((x < 0.f) ? -1.f : 0.f);
}

// fp32 row-major -> bf16 (packed), 4 elems/thread
__global__ void k_tobf16(const float* __restrict__ x, unsigned short* __restrict__ o, int n4) {
  int i = blockIdx.x * 256 + threadIdx.x;
  if (i >= n4) return;
  float4 v = ((const float4*)x)[i];
  uint2 p;
  p.x = (unsigned)f2bf(v.x) | ((unsigned)f2bf(v.y) << 16);
  p.y = (unsigned)f2bf(v.z) | ((unsigned)f2bf(v.w) << 16);
  ((uint2*)o)[i] = p;
}

// ---------------- CSR build (two-pass bucketed binning) ----------------
__global__ __launch_bounds__(512) void k_bhist(const int* __restrict__ rows, int nnz,
                                               int row_off, int shift,
                                               const unsigned char* __restrict__ flags,
                                               int* __restrict__ bcnt) {
  __shared__ int h[512];
  int t = threadIdx.x;
  h[t] = 0;
  __syncthreads();
  int tile0 = blockIdx.x * 8192;
#pragma unroll
  for (int i = 0; i < 16; ++i) {
    int e = tile0 + i * 512 + t;
    if (e < nnz) {
      int r = rows[e] + row_off;
      if (!flags || flags[r]) atomicAdd(&h[r >> shift], 1);
    }
  }
  __syncthreads();
  if (h[t]) atomicAdd(&bcnt[t], h[t]);
}

__global__ void k_bucket_scan(const int* __restrict__ bcnt, int nb, int* __restrict__ bbase,
                              int* __restrict__ bcur, int* __restrict__ rowptr_end) {
  int t = threadIdx.x;  // 512
  int lane = t & 63, w = t >> 6;
  int v = (t < nb) ? bcnt[t] : 0;
  int inc = v;
#pragma unroll
  for (int off = 1; off < 64; off <<= 1) {
    int y = __shfl_up(inc, off);
    if (lane >= off) inc += y;
  }
  __shared__ int wsum[8];
  if (lane == 63) wsum[w] = inc;
  __syncthreads();
  int wadd = 0;
  for (int i = 0; i < w; ++i) wadd += wsum[i];
  inc += wadd;
  if (t < nb) { bbase[t] = inc - v; bcur[t] = inc - v; }
  if (t == 511) { bbase[nb] = inc; *rowptr_end = inc; }
}

// entry packs (rowlocal<<20)|globalcol; gcol = col < nAth ? col+offA : col+offB
__global__ __launch_bounds__(512) void k_binscatter(const int* __restrict__ rows,
                                                    const int* __restrict__ cols,
                                                    const float* __restrict__ vals, int nnz,
                                                    int row_off, int shift,
                                                    int nAth, int offA, int offB,
                                                    const unsigned char* __restrict__ flags,
                                                    int* __restrict__ bcur,
                                                    int2* __restrict__ ebin_cv) {
  __shared__ int cnt[512];
  __shared__ int gbase[512];
  int t = threadIdx.x;
  int tile0 = blockIdx.x * 8192;
  cnt[t] = 0;
  __syncthreads();
  int r[16], rank[16];
#pragma unroll
  for (int i = 0; i < 16; ++i) {
    int e = tile0 + i * 512 + t;
    rank[i] = -1;
    if (e < nnz) {
      r[i] = rows[e] + row_off;
      if (!flags || flags[r[i]]) rank[i] = atomicAdd(&cnt[r[i] >> shift], 1);
    }
  }
  __syncthreads();
  int c = cnt[t];
  if (c > 0) gbase[t] = atomicAdd(&bcur[t], c);
  __syncthreads();
  int mask = (1 << shift) - 1;
#pragma unroll
  for (int i = 0; i < 16; ++i) {
    int e = tile0 + i * 512 + t;
    if (rank[i] >= 0) {
      int pos = gbase[r[i] >> shift] + rank[i];
      int col = cols[e];
      int gcol = (col < nAth) ? col + offA : col + offB;
      ebin_cv[pos] = make_int2(((r[i] & mask) << 20) | gcol, __float_as_int(vals[e]));
    }
  }
}

__global__ __launch_bounds__(1024) void k_place(const int* __restrict__ bbase, int shift,
                                                int nrows, const int2* __restrict__ ebin_cv,
                                                int* __restrict__ rowptr,
                                                int2* __restrict__ epack) {
  int b = blockIdx.x;
  int bsize = 1 << shift;
  int row0 = b << shift;
  int t = threadIdx.x;
  __shared__ int rcnt[1024];
  __shared__ int wsum[16];
  int ebase = bbase[b], eend = bbase[b + 1];
  if (t < bsize) rcnt[t] = 0;
  __syncthreads();
  for (int e = ebase + t; e < eend; e += 1024)
    atomicAdd(&rcnt[ebin_cv[e].x >> 20], 1);
  __syncthreads();
  int v = (t < bsize) ? rcnt[t] : 0;
  int inc = v;
  int lane = t & 63, w = t >> 6;
#pragma unroll
  for (int off = 1; off < 64; off <<= 1) {
    int y = __shfl_up(inc, off);
    if (lane >= off) inc += y;
  }
  if (lane == 63) wsum[w] = inc;
  __syncthreads();
  int wadd = 0;
  for (int i = 0; i < w; ++i) wadd += wsum[i];
  inc += wadd;
  int excl = inc - v;
  int nr = nrows - row0;
  if (nr > bsize) nr = bsize;
  if (t < nr) rowptr[row0 + t] = ebase + excl;
  __syncthreads();
  if (t < bsize) rcnt[t] = excl;  // reuse as cursor
  __syncthreads();
  for (int e = ebase + t; e < eend; e += 1024) {
    int2 cv = ebin_cv[e];
    int pos = ebase + atomicAdd(&rcnt[cv.x >> 20], 1);
    epack[pos] = make_int2(cv.x & 0xFFFFF, cv.y);
  }
}

// ---------------- fused gather SPMM (bf16 streams, 2 rows/wave) ----------------
// lane = h*32 + q*16 + c : h = row half, q = edge slot, c = dim lane (4 dims).
// Per iteration: 8 edges per row (4-deep j unroll x 2 slots).
__device__ __forceinline__ float4 gather_row_bf16(int s, int e, int q, unsigned cb,
                                                  const int2* __restrict__ epack,
                                                  const uint2* __restrict__ src) {
  int em1 = e - 1;
  f32x2 a0[4], a1[4];
#pragma unroll
  for (int j = 0; j < 4; ++j) { a0[j] = (f32x2){0.f, 0.f}; a1[j] = (f32x2){0.f, 0.f}; }
  for (int kk = s; kk < e; kk += 8) {
#pragma unroll
    for (int j = 0; j < 4; ++j) {
      int i = kk + 2 * j + q;
      i2v ed = __builtin_nontemporal_load((const i2v*)epack + min(i, em1));
      float v = (i <= em1) ? __int_as_float(ed.y) : 0.f;
      uint2 d = *(const uint2*)((const char*)src + (((unsigned)ed.x << 7) | cb));
      f32x2 lo = {__uint_as_float(d.x << 16), __uint_as_float(d.x & 0xffff0000u)};
      f32x2 hi = {__uint_as_float(d.y << 16), __uint_as_float(d.y & 0xffff0000u)};
      f32x2 vv = {v, v};
      a0[j] = __builtin_elementwise_fma(lo, vv, a0[j]);
      a1[j] = __builtin_elementwise_fma(hi, vv, a1[j]);
    }
  }
  f32x2 g0 = (a0[0] + a0[1]) + (a0[2] + a0[3]);
  f32x2 g1 = (a1[0] + a1[1]) + (a1[2] + a1[3]);
  float4 g = {g0.x, g0.y, g1.x, g1.y};
  // reduce over the q bit only (lane^16)
  g.x += __shfl_xor(g.x, 16); g.y += __shfl_xor(g.y, 16);
  g.z += __shfl_xor(g.z, 16); g.w += __shfl_xor(g.w, 16);
  return g;
}

// Layer 1 for all three graphs in one dispatch. Global rows:
// UB [0,70000), UI [70000,220000), BI [220000,340000). Boundaries even -> pair-uniform.
__global__ __launch_bounds__(256) void k_spmm1_all(
    const int* __restrict__ rowptr, const int2* __restrict__ epack,
    const uint2* __restrict__ xg, const float* __restrict__ nzUB,
    const float* __restrict__ nzUI, const float* __restrict__ nzBI,
    uint2* __restrict__ s2ub, uint2* __restrict__ s2ui, uint2* __restrict__ s2bi_adj) {
  long long t = (long long)blockIdx.x * 256 + threadIdx.x;
  int wv = (int)(t >> 6), lane = (int)(t & 63);
  if (wv >= 170000) return;
  int h = lane >> 5, q = (lane >> 4) & 1, c = lane & 15;
  unsigned cb = (unsigned)c << 3;
  int row = 2 * wv + h;
  const float* nrow;
  uint2* s2row;
  if (row < 70000) {
    nrow = nzUB + (size_t)row * DD;
    s2row = s2ub + (size_t)row * 16;
  } else if (row < 220000) {
    int lr = row - 70000;
    nrow = nzUI + (size_t)lr * DD;
    int node = (lr < 50000) ? lr : lr + 20000;
    s2row = s2ui + (size_t)node * 16;
  } else {
    int lr = row - 220000;
    nrow = nzBI + (size_t)lr * DD;
    s2row = s2bi_adj + (size_t)(lr + 50000) * 16;
  }
  int s = rowptr[row], e = rowptr[row + 1];
  float4 g = gather_row_bf16(s, e, q, cb, epack, xg);
  f4v nz = __builtin_nontemporal_load((const f4v*)nrow + c);
  float nn = wave_sum16(nz.x * nz.x + nz.y * nz.y + nz.z * nz.z + nz.w * nz.w) * 0.25f;
  float nf = 0.1f / fmaxf(sqrtf(nn), 1e-12f);
  if (q == 0) {
    float4 fv;
    fv.x = g.x + sgn(g.x) * nz.x * nf;
    fv.y = g.y + sgn(g.y) * nz.y * nf;
    fv.z = g.z + sgn(g.z) * nz.z * nf;
    fv.w = g.w + sgn(g.w) * nz.w * nf;
    uint2 o;
    o.x = (unsigned)f2bf(fv.x) | ((unsigned)f2bf(fv.y) << 16);
    o.y = (unsigned)f2bf(fv.z) | ((unsigned)f2bf(fv.w) << 16);
    s2row[c] = o;
  }
}

// shared layer-2 epilogue body
__device__ __forceinline__ void spmm2_body(int s, int e, int q, int c, unsigned cb,
                                           const int2* __restrict__ epack,
                                           const uint2* __restrict__ s2,
                                           const uint2* __restrict__ xg, int node,
                                           const float* __restrict__ nrow,
                                           float* __restrict__ orow) {
  float4 g = gather_row_bf16(s, e, q, cb, epack, s2);
  f4v nz = __builtin_nontemporal_load((const f4v*)nrow + c);
  float nn = wave_sum16(nz.x * nz.x + nz.y * nz.y + nz.z * nz.z + nz.w * nz.w) * 0.25f;
  float nf = 0.1f / fmaxf(sqrtf(nn), 1e-12f);
  float4 fv;
  fv.x = g.x + sgn(g.x) * nz.x * nf;
  fv.y = g.y + sgn(g.y) * nz.y * nf;
  fv.z = g.z + sgn(g.z) * nz.z * nf;
  fv.w = g.w + sgn(g.w) * nz.w * nf;
  float fn2 = wave_sum16(fv.x * fv.x + fv.y * fv.y + fv.z * fv.z + fv.w * fv.w) * 0.25f;
  float inv2 = (1.f / 3.f) / fmaxf(sqrtf(fn2), 1e-12f);
  uint2 s1p = s2[(size_t)node * 16 + c];
  float4 s1;
  s1.x = __uint_as_float(s1p.x << 16);
  s1.y = __uint_as_float(s1p.x & 0xffff0000u);
  s1.z = __uint_as_float(s1p.y << 16);
  s1.w = __uint_as_float(s1p.y & 0xffff0000u);
  float fn1 = wave_sum16(s1.x * s1.x + s1.y * s1.y + s1.z * s1.z + s1.w * s1.w) * 0.25f;
  float inv1 = (1.f / 3.f) / fmaxf(sqrtf(fn1), 1e-12f);
  uint2 x0p = xg[(size_t)node * 16 + c];
  float4 x0;
  x0.x = __uint_as_float(x0p.x << 16);
  x0.y = __uint_as_float(x0p.x & 0xffff0000u);
  x0.z = __uint_as_float(x0p.y << 16);
  x0.w = __uint_as_float(x0p.y & 0xffff0000u);
  if (q == 0) {
    float4 o;
    o.x = x0.x * (1.f / 3.f) + s1.x * inv1 + fv.x * inv2;
    o.y = x0.y * (1.f / 3.f) + s1.y * inv1 + fv.y * inv2;
    o.z = x0.z * (1.f / 3.f) + s1.z * inv1 + fv.z * inv2;
    o.w = x0.w * (1.f / 3.f) + s1.w * inv1 + fv.w * inv2;
    ((float4*)orow)[c] = o;
  }
}

// Item rows of UI (100K) then BI (100K), fused. 100000 waves.
__global__ __launch_bounds__(256) void k_spmm2_items(
    const int* __restrict__ rowptr, const int2* __restrict__ epack,
    const uint2* __restrict__ xg, const uint2* __restrict__ s2ui,
    const uint2* __restrict__ s2bi_adj, const float* __restrict__ nzUI,
    const float* __restrict__ nzBI, float* __restrict__ o_UIit,
    float* __restrict__ o_BIit) {
  long long t = (long long)blockIdx.x * 256 + threadIdx.x;
  int wv = (int)(t >> 6), lane = (int)(t & 63);
  if (wv >= 100000) return;
  int h = lane >> 5, q = (lane >> 4) & 1, c = lane & 15;
  unsigned cb = (unsigned)c << 3;
  const uint2* s2;
  const float* nrow;
  float* orow;
  int grow, node;
  if (wv < 50000) {
    int ii = 2 * wv + h;
    grow = 120000 + ii;
    node = 70000 + ii;
    s2 = s2ui;
    nrow = nzUI + (size_t)(200000 + ii) * DD;
    orow = o_UIit + (size_t)ii * DD;
  } else {
    int ii = 2 * (wv - 50000) + h;
    grow = 240000 + ii;
    node = 70000 + ii;
    s2 = s2bi_adj;
    nrow = nzBI + (size_t)(140000 + ii) * DD;
    orow = o_BIit + (size_t)ii * DD;
  }
  int s = rowptr[grow], e = rowptr[grow + 1];
  spmm2_body(s, e, q, c, cb, epack, s2, xg, node, nrow, orow);
}

// Sampled layer-2 rows: UBu(2048) UBb(4096) UIu(2048) BIb(4096). 6144 waves.
__global__ __launch_bounds__(256) void k_spmm2_samp(
    const int* __restrict__ rowptr, const int2* __restrict__ epack,
    const uint2* __restrict__ xg, const uint2* __restrict__ s2ub,
    const uint2* __restrict__ s2ui, const uint2* __restrict__ s2bi_adj,
    const float* __restrict__ nzUB, const float* __restrict__ nzUI,
    const float* __restrict__ nzBI, const int* __restrict__ users,
    const int* __restrict__ bundles, float* __restrict__ o_UBS,
    float* __restrict__ o_UIuS, float* __restrict__ o_BIbS) {
  long long t = (long long)blockIdx.x * 256 + threadIdx.x;
  int wv = (int)(t >> 6), lane = (int)(t & 63);
  if (wv >= 6144) return;
  int h = lane >> 5, q = (lane >> 4) & 1, c = lane & 15;
  unsigned cb = (unsigned)c << 3;
  const uint2* s2;
  const float* nrow;
  float* orow;
  int grow, node;
  if (wv < 1024) {
    int ii = 2 * wv + h;
    int id = users[ii];
    grow = id; node = id; s2 = s2ub;
    nrow = nzUB + (size_t)(70000 + id) * DD;
    orow = o_UBS + (size_t)ii * DD;
  } else if (wv < 3072) {
    int ii = 2 * (wv - 1024) + h;
    int id = bundles[ii];
    node = 50000 + id; grow = node; s2 = s2ub;
    nrow = nzUB + (size_t)(70000 + node) * DD;
    orow = o_UBS + (size_t)(2048 + ii) * DD;
  } else if (wv < 4096) {
    int ii = 2 * (wv - 3072) + h;
    int id = users[ii];
    grow = 70000 + id; node = id; s2 = s2ui;
    nrow = nzUI + (size_t)(150000 + id) * DD;
    orow = o_UIuS + (size_t)ii * DD;
  } else {
    int ii = 2 * (wv - 4096) + h;
    int id = bundles[ii];
    grow = 220000 + id; node = 50000 + id; s2 = s2bi_adj;
    nrow = nzBI + (size_t)(120000 + id) * DD;
    orow = o_BIbS + (size_t)ii * DD;
  }
  int s = rowptr[grow], e = rowptr[grow + 1];
  spmm2_body(s, e, q, c, cb, epack, s2, xg, node, nrow, orow);
}

// Fused sampled aggregation: uib (4096 rows) then biu (2048 rows). 3072 waves. fp32 gather.
__global__ __launch_bounds__(256) void k_agg2(
    const int* __restrict__ rowptr, const int2* __restrict__ epack,
    const float* __restrict__ o_UIit, const float* __restrict__ o_BIit,
    const float* __restrict__ nzBA, const float* __restrict__ nzUA,
    const int* __restrict__ users, const int* __restrict__ bundles,
    float* __restrict__ uibS, float* __restrict__ biuS) {
  long long t = (long long)blockIdx.x * 256 + threadIdx.x;
  int wv = (int)(t >> 6), lane = (int)(t & 63);
  if (wv >= 3072) return;
  int h = lane >> 5, q = (lane >> 4) & 1, c = lane & 15;
  const float* x;
  const float* nrow;
  float* orow;
  int grow;
  if (wv < 2048) {
    int ii = 2 * wv + h;
    int id = bundles[ii];
    grow = id; x = o_UIit;
    nrow = nzBA + (size_t)id * DD;
    orow = uibS + (size_t)ii * DD;
  } else {
    int ii = 2 * (wv - 2048) + h;
    int id = users[ii];
    grow = 20000 + id; x = o_BIit;
    nrow = nzUA + (size_t)id * DD;
    orow = biuS + (size_t)ii * DD;
  }
  int s = rowptr[grow], e = rowptr[grow + 1];
  int em1 = e - 1;
  float4 a[4];
#pragma unroll
  for (int j = 0; j < 4; ++j) a[j] = (float4){0.f, 0.f, 0.f, 0.f};
  for (int kk = s; kk < e; kk += 8) {
#pragma unroll
    for (int j = 0; j < 4; ++j) {
      int i = kk + 2 * j + q;
      i2v ed = __builtin_nontemporal_load((const i2v*)epack + min(i, em1));
      float v = (i <= em1) ? __int_as_float(ed.y) : 0.f;
      float4 xv = ((const float4*)(x + (size_t)ed.x * DD))[c];
      a[j].x = fmaf(v, xv.x, a[j].x); a[j].y = fmaf(v, xv.y, a[j].y);
      a[j].z = fmaf(v, xv.z, a[j].z); a[j].w = fmaf(v, xv.w, a[j].w);
    }
  }
  float4 g;
  g.x = (a[0].x + a[1].x) + (a[2].x + a[3].x);
  g.y = (a[0].y + a[1].y) + (a[2].y + a[3].y);
  g.z = (a[0].z + a[1].z) + (a[2].z + a[3].z);
  g.w = (a[0].w + a[1].w) + (a[2].w + a[3].w);
  g.x += __shfl_xor(g.x, 16); g.y += __shfl_xor(g.y, 16);
  g.z += __shfl_xor(g.z, 16); g.w += __shfl_xor(g.w, 16);
  f4v nz = __builtin_nontemporal_load((const f4v*)nrow + c);
  float nn = wave_sum16(nz.x * nz.x + nz.y * nz.y + nz.z * nz.z + nz.w * nz.w) * 0.25f;
  float nf = 0.1f / fmaxf(sqrtf(nn), 1e-12f);
  if (q == 0) {
    float4 fv;
    fv.x = g.x + sgn(g.x) * nz.x * nf;
    fv.y = g.y + sgn(g.y) * nz.y * nf;
    fv.z = g.z + sgn(g.z) * nz.z * nf;
    fv.w = g.w + sgn(g.w) * nz.w * nf;
    ((float4*)orow)[c] = fv;
  }
}

// set sampled-row flags for phase-2 filtering (biagg rows [0,20000), uiagg [20000,70000))
__global__ void k_flag(const int* __restrict__ users, const int* __restrict__ bundles,
                       unsigned char* __restrict__ flags) {
  int t = blockIdx.x * 256 + threadIdx.x;
  if (t < BATCH) flags[20000 + users[t]] = 1;
  if (t < 2 * BATCH) flags[bundles[t]] = 1;
}

// ---------------- heads ----------------
__global__ void k_bpr(const float* __restrict__ o_UIuS, const float* __restrict__ biuS,
                      const float* __restrict__ uibS, const float* __restrict__ o_BIbS,
                      float* __restrict__ bpr_terms) {
  long long t = (long long)blockIdx.x * 256 + threadIdx.x;
  int w = (int)(t >> 6);
  int lane = (int)(t & 63);
  if (w >= BATCH) return;
  float ur = 0.5f * (o_UIuS[(size_t)w * DD + lane] + biuS[(size_t)w * DD + lane]);
  float br0 = 0.5f * (uibS[(size_t)(2 * w) * DD + lane] + o_BIbS[(size_t)(2 * w) * DD + lane]);
  float br1 = 0.5f * (uibS[(size_t)(2 * w + 1) * DD + lane] +
                      o_BIbS[(size_t)(2 * w + 1) * DD + lane]);
  float pos = wave_sum(ur * br0);
  float neg = wave_sum(ur * br1);
  if (lane == 0) {
    float x = pos - neg;
    float loss = (x > 0.f) ? log1pf(expf(-x)) : (-x + log1pf(expf(x)));
    bpr_terms[w] = loss;
  }
}

__global__ void k_sumsq_p(const float* __restrict__ x, int n4, float* __restrict__ partials) {
  float s = 0.f;
  for (int i = blockIdx.x * 256 + threadIdx.x; i < n4; i += gridDim.x * 256) {
    float4 v = ((const float4*)x)[i];
    s += v.x * v.x + v.y * v.y + v.z * v.z + v.w * v.w;
  }
  s = wave_sum(s);
  __shared__ float part[4];
  if ((threadIdx.x & 63) == 0) part[threadIdx.x >> 6] = s;
  __syncthreads();
  if (threadIdx.x == 0) partials[blockIdx.x] = part[0] + part[1] + part[2] + part[3];
}

__global__ void k_gather(const float* __restrict__ o_UBS, const float* __restrict__ o_UIuS,
                         const float* __restrict__ o_BIbS, const float* __restrict__ uibS,
                         const float* __restrict__ biuS, float* __restrict__ P,
                         unsigned short* __restrict__ Pb) {
  long long t = (long long)blockIdx.x * 256 + threadIdx.x;
  int w = (int)(t >> 6);
  int lane = (int)(t & 63);
  if (w >= 6 * BATCH) return;
  int k = w / BATCH, b = w % BATCH;
  const float* src;
  if (k == 0)      src = o_UBS + (size_t)b * DD;
  else if (k == 1) src = o_UIuS + (size_t)b * DD;
  else if (k == 2) src = biuS + (size_t)b * DD;
  else if (k == 3) src = o_UBS + (size_t)(2048 + 2 * b) * DD;
  else if (k == 4) src = uibS + (size_t)(2 * b) * DD;
  else             src = o_BIbS + (size_t)(2 * b) * DD;
  float v = src[lane];
  float n2 = wave_sum(v * v);
  float inv = 1.f / fmaxf(sqrtf(n2), 1e-12f);
  float pv = v * inv;
  P[(size_t)w * DD + lane] = pv;
  Pb[(size_t)w * DD + lane] = f2bf(pv);
}

__global__ void k_clpair_mfma(const unsigned short* __restrict__ Pb,
                              float* __restrict__ ttl) {
  const int pairX[12] = {0, 0, 1, 0, 1, 2, 3, 3, 4, 3, 4, 5};
  const int pairY[12] = {1, 2, 2, 0, 1, 2, 4, 5, 5, 3, 4, 5};
  int wid = threadIdx.x >> 6;
  int lane = threadIdx.x & 63;
  int wtile = blockIdx.x * 4 + wid;
  int p = wtile >> 8;
  int rest = wtile & 255;
  int it = rest >> 3, jc = rest & 7;
  const unsigned short* X = Pb + (size_t)pairX[p] * BATCH * DD;
  const unsigned short* Y = Pb + (size_t)pairY[p] * BATCH * DD;
  int r = lane & 15, q = lane >> 4;
  short8 A[2][4];
#pragma unroll
  for (int kh = 0; kh < 2; ++kh)
#pragma unroll
    for (int ii = 0; ii < 4; ++ii)
      A[kh][ii] = *(const short8*)(X + (size_t)(it * 64 + ii * 16 + r) * DD + kh * 32 + q * 8);
  float rs[4][4];
#pragma unroll
  for (int ii = 0; ii < 4; ++ii)
#pragma unroll
    for (int g = 0; g < 4; ++g) rs[ii][g] = 0.f;
  for (int jn = 0; jn < 4; ++jn) {
    int j0 = jc * 256 + jn * 64;
    floatx4 acc[4][4];
#pragma unroll
    for (int ii = 0; ii < 4; ++ii)
#pragma unroll
      for (int jj = 0; jj < 4; ++jj) acc[ii][jj] = (floatx4){0.f, 0.f, 0.f, 0.f};
#pragma unroll
    for (int kh = 0; kh < 2; ++kh) {
      short8 Bf[4];
#pragma unroll
      for (int jj = 0; jj < 4; ++jj)
        Bf[jj] = *(const short8*)(Y + (size_t)(j0 + jj * 16 + r) * DD + kh * 32 + q * 8);
#pragma unroll
      for (int ii = 0; ii < 4; ++ii)
#pragma unroll
        for (int jj = 0; jj < 4; ++jj)
          acc[ii][jj] = __builtin_amdgcn_mfma_f32_16x16x32_bf16(A[kh][ii], Bf[jj],
                                                                acc[ii][jj], 0, 0, 0);
    }
#pragma unroll
    for (int ii = 0; ii < 4; ++ii)
#pragma unroll
      for (int jj = 0; jj < 4; ++jj)
#pragma unroll
        for (int g = 0; g < 4; ++g) rs[ii][g] += __expf(4.0f * acc[ii][jj][g]);
  }
#pragma unroll
  for (int off = 1; off < 16; off <<= 1)
#pragma unroll
    for (int ii = 0; ii < 4; ++ii)
#pragma unroll
      for (int g = 0; g < 4; ++g) rs[ii][g] += __shfl_xor(rs[ii][g], off);
  if (r == 0) {
#pragma unroll
    for (int ii = 0; ii < 4; ++ii)
#pragma unroll
      for (int g = 0; g < 4; ++g)
        unsafeAtomicAdd(&ttl[(size_t)p * BATCH + it * 64 + ii * 16 + q * 4 + g],
                        rs[ii][g]);
  }
}

__global__ void k_cldiag(const float* __restrict__ P, float* __restrict__ ttl) {
  const int pairX[12] = {0, 0, 1, 0, 1, 2, 3, 3, 4, 3, 4, 5};
  const int pairY[12] = {1, 2, 2, 0, 1, 2, 4, 5, 5, 3, 4, 5};
  long long t = (long long)blockIdx.x * 256 + threadIdx.x;
  int w = (int)(t >> 6);
  int lane = (int)(t & 63);
  if (w >= 12 * BATCH) return;
  int p = w / BATCH, i = w % BATCH;
  float xv = P[((size_t)pairX[p] * BATCH + i) * DD + lane];
  float yv = P[((size_t)pairY[p] * BATCH + i) * DD + lane];
  float d = wave_sum(xv * yv);
  if (lane == 0) ttl[(size_t)p * BATCH + i] = logf(ttl[(size_t)p * BATCH + i]) - d * 4.0f;
}

__global__ void k_finalred(const float* __restrict__ bpr_terms,
                           const float* __restrict__ cl_terms,
                           const float* __restrict__ partials,
                           float* __restrict__ out) {
  int t = threadIdx.x;  // 1024
  float bpr = 0.f, reg = 0.f, inter = 0.f, intra = 0.f;
  for (int i = t; i < BATCH; i += 1024) bpr += bpr_terms[i];
  for (int i = t; i < 768; i += 1024) reg += partials[i];
  for (int i = t; i < 12 * BATCH; i += 1024) {
    int p = i >> 11;
    float v = cl_terms[i];
    if ((p % 6) < 3) inter += v; else intra += v;
  }
  bpr = wave_sum(bpr); reg = wave_sum(reg);
  inter = wave_sum(inter); intra = wave_sum(intra);
  __shared__ float sb[16], sr[16], si[16], sx[16];
  int w = t >> 6, lane = t & 63;
  if (lane == 0) { sb[w] = bpr; sr[w] = reg; si[w] = inter; sx[w] = intra; }
  __syncthreads();
  if (t == 0) {
    float Bs = 0, Rs = 0, Is = 0, Xs = 0;
    for (int i = 0; i < 16; ++i) { Bs += sb[i]; Rs += sr[i]; Is += si[i]; Xs += sx[i]; }
    out[0] = Bs / (float)BATCH + 1e-5f * Rs;
    out[1] = 0.04f * (0.5f * Is + 0.5f * Xs) / (float)BATCH;
  }
}

}  // namespace

extern "C" void kernel_launch(void* const* d_in, const int* in_sizes, int n_in,
                              void* d_out, int out_size, void* d_ws, size_t ws_size,
                              hipStream_t stream) {
  const float* usersF = (const float*)d_in[0];
  const float* bundlesF = (const float*)d_in[1];
  const float* itemsF = (const float*)d_in[2];
  const int* ub_rows = (const int*)d_in[3];
  const int* ub_cols = (const int*)d_in[4];
  const float* ub_vals = (const float*)d_in[5];
  const int* ui_rows = (const int*)d_in[6];
  const int* ui_cols = (const int*)d_in[7];
  const float* ui_vals = (const float*)d_in[8];
  const int* bi_rows = (const int*)d_in[9];
  const int* bi_cols = (const int*)d_in[10];
  const float* bi_vals = (const float*)d_in[11];
  const int* biagg_rows = (const int*)d_in[12];
  const int* biagg_cols = (const int*)d_in[13];
  const float* biagg_vals = (const float*)d_in[14];
  const int* uiagg_rows = (const int*)d_in[15];
  const int* uiagg_cols = (const int*)d_in[16];
  const float* uiagg_vals = (const float*)d_in[17];
  const float* noise_UB = (const float*)d_in[18];
  const float* noise_UI = (const float*)d_in[19];
  const float* noise_BI = (const float*)d_in[20];
  const float* noise_agg_BI = (const float*)d_in[21];
  const float* noise_agg_UI = (const float*)d_in[22];
  const int* users = (const int*)d_in[23];
  const int* bundles = (const int*)d_in[24];
  int nnz_ub = in_sizes[3], nnz_ui = in_sizes[6], nnz_bi = in_sizes[9];
  int nnz_biagg = in_sizes[12], nnz_uiagg = in_sizes[15];

  float* ws = (float*)d_ws;
  size_t off = 0;
  float* o_UBS  = ws + off; off += (size_t)(3 * BATCH) * DD;
  float* o_UIuS = ws + off; off += (size_t)BATCH * DD;
  float* o_UIit = ws + off; off += (size_t)I_N * DD;
  float* o_BIbS = ws + off; off += (size_t)(2 * BATCH) * DD;
  float* o_BIit = ws + off; off += (size_t)I_N * DD;
  float* uibS = ws + off; off += (size_t)2 * BATCH * DD;
  float* biuS = ws + off; off += (size_t)BATCH * DD;
  // per-graph layer-1 bf16 buffers (node-indexed)
  unsigned short* s2ub16 = (unsigned short*)(ws + off); off += (size_t)70000 * DD / 2;
  unsigned short* s2ui16 = (unsigned short*)(ws + off); off += (size_t)170000 * DD / 2;
  unsigned short* s2bi16 = (unsigned short*)(ws + off); off += (size_t)120000 * DD / 2;
  unsigned short* xb16   = (unsigned short*)(ws + off); off += (size_t)170000 * DD / 2;
  float* P    = ws + off; off += (size_t)6 * BATCH * DD;
  float* ttl  = ws + off; off += (size_t)12 * BATCH;
  float* bprT = ws + off; off += BATCH;
  float* prt  = ws + off; off += 768;
  int* rptr  = (int*)(ws + off); off += N1 + 1;
  int* bcnt  = (int*)(ws + off); off += 512;
  int* bbase = (int*)(ws + off); off += 520;
  int* bcur  = (int*)(ws + off); off += 512;
  unsigned char* flags = (unsigned char*)(ws + off); off += 17500;  // 70000 B
  off = (off + 1) & ~(size_t)1;  // 8B align
  int2* epack = (int2*)(ws + off); off += (size_t)5200000 * 2;
  if (ws_size < off * sizeof(float)) return;  // insufficient workspace

  // aliases:
  // phase-1 binning staging: o_* chain (13.58M floats >= 10.4M), consumed by k_place
  int2* ebin_cv1 = (int2*)ws;
  // phase-2 binning staging: s2ui region (5.44M floats; s2 dead after spmm2s)
  int2* ebin_cv2 = (int2*)s2ui16;
  // Pb (bf16 of P): s2ub region (needs 393K floats <= 2.24M)
  unsigned short* Pb = s2ub16;

  const uint2* xgv = (const uint2*)xb16;
  uint2* s2ub = (uint2*)s2ub16;
  uint2* s2ui = (uint2*)s2ui16;
  uint2* s2bi_adj = (uint2*)s2bi16 - (size_t)50000 * 16;  // index by node id (>=50000)

  auto gb = [](int nnz) { return (nnz + 8191) / 8192; };

  // ---- bf16 conversion of input features into concat [users|bundles|items]
  k_tobf16<<<(U_N * 16 + 255) / 256, 256, 0, stream>>>(usersF, xb16, U_N * 16);
  k_tobf16<<<(B_N * 16 + 255) / 256, 256, 0, stream>>>(bundlesF, xb16 + (size_t)U_N * DD,
                                                       B_N * 16);
  k_tobf16<<<(I_N * 16 + 255) / 256, 256, 0, stream>>>(itemsF, xb16 + (size_t)(U_N + B_N) * DD,
                                                       I_N * 16);

  // ---- phase-1 CSR: UB rows [0,70000), UI rows [70000,220000), BI rows [220000,340000)
  // cols remapped to node space: UB identity; UI u->u, item->+20000; BI all->+50000
  hipMemsetAsync(bcnt, 0, 512 * sizeof(int), stream);
  k_bhist<<<gb(nnz_ub), 512, 0, stream>>>(ub_rows, nnz_ub, 0, SHIFT1, nullptr, bcnt);
  k_bhist<<<gb(nnz_ui), 512, 0, stream>>>(ui_rows, nnz_ui, 70000, SHIFT1, nullptr, bcnt);
  k_bhist<<<gb(nnz_bi), 512, 0, stream>>>(bi_rows, nnz_bi, 220000, SHIFT1, nullptr, bcnt);
  k_bucket_scan<<<1, 512, 0, stream>>>(bcnt, NB1, bbase, bcur, rptr + N1);
  k_binscatter<<<gb(nnz_ub), 512, 0, stream>>>(ub_rows, ub_cols, ub_vals, nnz_ub, 0, SHIFT1,
                                               INT_MAX, 0, 0, nullptr, bcur, ebin_cv1);
  k_binscatter<<<gb(nnz_ui), 512, 0, stream>>>(ui_rows, ui_cols, ui_vals, nnz_ui, 70000, SHIFT1,
                                               50000, 0, 20000, nullptr, bcur, ebin_cv1);
  k_binscatter<<<gb(nnz_bi), 512, 0, stream>>>(bi_rows, bi_cols, bi_vals, nnz_bi, 220000, SHIFT1,
                                               0, 50000, 50000, nullptr, bcur, ebin_cv1);
  k_place<<<NB1, 1024, 0, stream>>>(bbase, SHIFT1, N1, ebin_cv1, rptr, epack);

  // ---- fused layer-1 (all graphs), then fused layer-2 dispatches
  k_spmm1_all<<<42500, 256, 0, stream>>>(rptr, epack, xgv, noise_UB, noise_UI, noise_BI,
                                         s2ub, s2ui, s2bi_adj);
  k_spmm2_items<<<25000, 256, 0, stream>>>(rptr, epack, xgv, s2ui, s2bi_adj,
                                           noise_UI, noise_BI, o_UIit, o_BIit);
  k_spmm2_samp<<<1536, 256, 0, stream>>>(rptr, epack, xgv, s2ub, s2ui, s2bi_adj,
                                         noise_UB, noise_UI, noise_BI, users, bundles,
                                         o_UBS, o_UIuS, o_BIbS);

  // ---- phase-2 CSR (sampled-row filtered): BIAGG rows [0,20000), UIAGG rows [20000,70000)
  hipMemsetAsync(flags, 0, 70000, stream);
  k_flag<<<(2 * BATCH + 255) / 256, 256, 0, stream>>>(users, bundles, flags);
  hipMemsetAsync(bcnt, 0, 512 * sizeof(int), stream);
  k_bhist<<<gb(nnz_biagg), 512, 0, stream>>>(biagg_rows, nnz_biagg, 0, SHIFT2, flags, bcnt);
  k_bhist<<<gb(nnz_uiagg), 512, 0, stream>>>(uiagg_rows, nnz_uiagg, 20000, SHIFT2, flags, bcnt);
  k_bucket_scan<<<1, 512, 0, stream>>>(bcnt, NB2, bbase, bcur, rptr + N2);
  k_binscatter<<<gb(nnz_biagg), 512, 0, stream>>>(biagg_rows, biagg_cols, biagg_vals, nnz_biagg,
                                                  0, SHIFT2, INT_MAX, 0, 0, flags, bcur,
                                                  ebin_cv2);
  k_binscatter<<<gb(nnz_uiagg), 512, 0, stream>>>(uiagg_rows, uiagg_cols, uiagg_vals, nnz_uiagg,
                                                  20000, SHIFT2, INT_MAX, 0, 0, flags, bcur,
                                                  ebin_cv2);
  k_place<<<NB2, 1024, 0, stream>>>(bbase, SHIFT2, N2, ebin_cv2, rptr, epack);

  // fused sampled aggregations
  k_agg2<<<768, 256, 0, stream>>>(rptr, epack, o_UIit, o_BIit, noise_agg_BI, noise_agg_UI,
                                  users, bundles, uibS, biuS);

  // heads
  k_bpr<<<BATCH * 64 / 256, 256, 0, stream>>>(o_UIuS, biuS, uibS, o_BIbS, bprT);
  k_sumsq_p<<<256, 256, 0, stream>>>(usersF, U_N * DD / 4, prt);
  k_sumsq_p<<<256, 256, 0, stream>>>(bundlesF, B_N * DD / 4, prt + 256);
  k_sumsq_p<<<256, 256, 0, stream>>>(itemsF, I_N * DD / 4, prt + 512);
  k_gather<<<6 * BATCH * 64 / 256, 256, 0, stream>>>(o_UBS, o_UIuS, o_BIbS, uibS, biuS,
                                                     P, Pb);
  hipMemsetAsync(ttl, 0, (size_t)12 * BATCH * sizeof(float), stream);
  k_clpair_mfma<<<768, 256, 0, stream>>>(Pb, ttl);
  k_cldiag<<<12 * BATCH * 64 / 256, 256, 0, stream>>>(P, ttl);
  k_finalred<<<1, 1024, 0, stream>>>(bprT, ttl, prt, (float*)d_out);
}